// Round 4
// baseline (121.162 us; speedup 1.0000x reference)
//
#include <hip/hip_runtime.h>
#include <hip/hip_bf16.h>

#define NHID 512
#define PROJ 64
#define NC 4096
#define NEV 8192
#define NG 64
#define NCMAX 128
#define NE_CAP 256
#define DSLICES 4
#define DW 128

typedef __attribute__((ext_vector_type(8))) short s16x8;
typedef __attribute__((ext_vector_type(8))) unsigned short u16x8;
typedef __attribute__((ext_vector_type(4))) float f32x4;

// ---- k_attn LDS layout (bytes) ----
#define P_S_STRIDE 264            // bf16 elems per row (256 + 8 pad), 528B
#define P_S_BYTES  (NCMAX * P_S_STRIDE * 2)        // 67584
#define REGB_OFF   P_S_BYTES
#define WE_S_STRIDE 72            // bf16 elems (64 + 8 pad), 144B
#define WC_S_OFF   (REGB_OFF + NE_CAP * WE_S_STRIDE * 2)
#define CN_S_STRIDE 132           // f32 elems per row
#define MISC_OFF   (REGB_OFF + P_S_BYTES)
#define PP_OFF     (MISC_OFF + 1536)               // 3*4*128 floats = 6144B
#define SMEM_BYTES (PP_OFF + 6144)

static __device__ __forceinline__ unsigned short f2b(float f) {
  union { __hip_bfloat16 h; unsigned short u; } v;
  v.h = __float2bfloat16(f);
  return v.u;
}

// ---------------- k_pre: gather graph ids ----------------
__global__ void k_pre(const int* __restrict__ batch, const int* __restrict__ cidx,
                      const int* __restrict__ eidx, int* __restrict__ cb,
                      int* __restrict__ eb) {
  int i = blockIdx.x * 256 + threadIdx.x;
  if (i < NC) cb[i] = batch[cidx[i]];
  int j = i - NC;
  if (j >= 0 && j < NEV) eb[j] = batch[eidx[j]];
}

// ---------------- k_compact: stable per-graph compaction ----------------
__device__ void compact_one(const int* __restrict__ arr, int n, int g,
                            int* __restrict__ off_out, int* __restrict__ cnt_out,
                            int* __restrict__ list) {
  int t = threadIdx.x;
  int lane = t & 63, w = t >> 6;
  __shared__ int wsum[4];
  __shared__ int sless[4];
  int less = 0;
  for (int i = t; i < n; i += 256) less += (arr[i] < g) ? 1 : 0;
#pragma unroll
  for (int off = 32; off; off >>= 1) less += __shfl_xor(less, off);
  if (lane == 0) sless[w] = less;
  __syncthreads();
  int base = sless[0] + sless[1] + sless[2] + sless[3];
  if (t == 0) off_out[g] = base;
  int wbase = base;
  for (int chunk = 0; chunk < n; chunk += 256) {
    int i = chunk + t;
    bool f = (i < n) && (arr[i] == g);
    unsigned long long m = __ballot(f);
    if (lane == 0) wsum[w] = __popcll(m);
    __syncthreads();
    int prefix = 0;
    for (int k = 0; k < w; k++) prefix += wsum[k];
    int total = wsum[0] + wsum[1] + wsum[2] + wsum[3];
    if (f) list[wbase + prefix + __popcll(m & ((1ull << (unsigned)lane) - 1ull))] = i;
    wbase += total;
    __syncthreads();
  }
  if (t == 0) cnt_out[g] = wbase - base;
  __syncthreads();
}

__global__ __launch_bounds__(256) void k_compact(
    const int* __restrict__ cb, const int* __restrict__ eb,
    int* __restrict__ c_off, int* __restrict__ c_cnt, int* __restrict__ c_list,
    int* __restrict__ e_off, int* __restrict__ e_cnt, int* __restrict__ e_list) {
  int g = blockIdx.x;
  compact_one(cb, NC, g, c_off, c_cnt, c_list);
  compact_one(eb, NEV, g, e_off, e_cnt, e_list);
}

// ---------------- k_t64: f32 [K][N] -> bf16 [N][K] tile transpose ----------------
__global__ __launch_bounds__(256) void k_t64(
    const float* __restrict__ Wc, const float* __restrict__ We,
    const float* __restrict__ Wa, unsigned short* __restrict__ WcT,
    unsigned short* __restrict__ WeT, unsigned short* __restrict__ WaT) {
  __shared__ float ts[64][65];
  int b = blockIdx.x;
  const float* src; unsigned short* dst; int K, N, kt, nt;
  if (b < 8)       { src = Wc; dst = WcT; K = 512;  N = 64;  kt = b;          nt = 0; }
  else if (b < 16) { src = We; dst = WeT; K = 512;  N = 64;  kt = b - 8;      nt = 0; }
  else             { src = Wa; dst = WaT; K = 2048; N = 512; kt = (b - 16) >> 3; nt = (b - 16) & 7; }
  int k0 = kt * 64, n0 = nt * 64;
  int t = threadIdx.x;
  int c = t & 63, r0 = t >> 6;
#pragma unroll
  for (int p = 0; p < 16; p++) {
    int r = r0 * 16 + p;
    ts[r][c] = src[(size_t)(k0 + r) * N + n0 + c];
  }
  __syncthreads();
  int n = t >> 2, q = t & 3;
  unsigned short tmp[16];
#pragma unroll
  for (int j = 0; j < 16; j++) tmp[j] = f2b(ts[q * 16 + j][n]);
  u16x8* dp = (u16x8*)(dst + (size_t)(n0 + n) * K + k0 + q * 16);
  dp[0] = *(u16x8*)tmp;
  dp[1] = *(u16x8*)(tmp + 8);
}

// ---------------- k_proj: MFMA GEMM, no LDS; out = bf16 ----------------
__global__ __launch_bounds__(128) void k_proj(
    const float* __restrict__ x, const int* __restrict__ cidx,
    const int* __restrict__ eidx, const unsigned short* __restrict__ WcT,
    const unsigned short* __restrict__ WeT, const float* __restrict__ bc,
    const float* __restrict__ be, unsigned short* __restrict__ wcp,
    unsigned short* __restrict__ wep) {
  int b = blockIdx.x;
  const int* idx; const unsigned short* WT; const float* bias;
  unsigned short* out; int base;
  if (b < NC / 64) { idx = cidx; WT = WcT; bias = bc; out = wcp; base = b * 64; }
  else             { idx = eidx; WT = WeT; bias = be; out = wep; base = (b - NC / 64) * 64; }
  int t = threadIdx.x, lane = t & 63, w = t >> 6;
  int ln = lane & 15, kb = lane >> 4;
  int m0 = w * 32;
  const float* xr0 = x + (size_t)idx[base + m0 + ln] * NHID;
  const float* xr1 = x + (size_t)idx[base + m0 + 16 + ln] * NHID;
  float bv[4];
#pragma unroll
  for (int nt = 0; nt < 4; nt++) bv[nt] = bias[nt * 16 + ln];
  f32x4 acc[2][4];
#pragma unroll
  for (int mi = 0; mi < 2; mi++)
#pragma unroll
    for (int nt = 0; nt < 4; nt++) acc[mi][nt] = (f32x4){0.f, 0.f, 0.f, 0.f};

#pragma unroll
  for (int kt = 0; kt < 8; kt++) {
#pragma unroll
    for (int ks = 0; ks < 2; ks++) {
      int k0 = kt * 64 + ks * 32 + kb * 8;
      float4 p0 = *(const float4*)(xr0 + k0);
      float4 p1 = *(const float4*)(xr0 + k0 + 4);
      float4 q0 = *(const float4*)(xr1 + k0);
      float4 q1 = *(const float4*)(xr1 + k0 + 4);
      s16x8 a0, a1;
      a0[0] = (short)f2b(p0.x); a0[1] = (short)f2b(p0.y);
      a0[2] = (short)f2b(p0.z); a0[3] = (short)f2b(p0.w);
      a0[4] = (short)f2b(p1.x); a0[5] = (short)f2b(p1.y);
      a0[6] = (short)f2b(p1.z); a0[7] = (short)f2b(p1.w);
      a1[0] = (short)f2b(q0.x); a1[1] = (short)f2b(q0.y);
      a1[2] = (short)f2b(q0.z); a1[3] = (short)f2b(q0.w);
      a1[4] = (short)f2b(q1.x); a1[5] = (short)f2b(q1.y);
      a1[6] = (short)f2b(q1.z); a1[7] = (short)f2b(q1.w);
#pragma unroll
      for (int nt = 0; nt < 4; nt++) {
        s16x8 bf = *(const s16x8*)(WT + (size_t)(nt * 16 + ln) * NHID + k0);
        acc[0][nt] = __builtin_amdgcn_mfma_f32_16x16x32_bf16(a0, bf, acc[0][nt], 0, 0, 0);
        acc[1][nt] = __builtin_amdgcn_mfma_f32_16x16x32_bf16(a1, bf, acc[1][nt], 0, 0, 0);
      }
    }
  }
#pragma unroll
  for (int mi = 0; mi < 2; mi++)
#pragma unroll
    for (int nt = 0; nt < 4; nt++)
#pragma unroll
      for (int r = 0; r < 4; r++) {
        int rowg = base + m0 + mi * 16 + kb * 4 + r;
        out[(size_t)rowg * PROJ + nt * 16 + ln] = f2b(acc[mi][nt][r] + bv[nt]);
      }
}

// ---------------- k_attn: MFMA block-diagonal attention, no atomics ----------------
__global__ __launch_bounds__(512) void k_attn(
    const float* __restrict__ x, const int* __restrict__ cidx,
    const int* __restrict__ eidx, const unsigned short* __restrict__ wcp,
    const unsigned short* __restrict__ wep, const int* __restrict__ c_off,
    const int* __restrict__ c_cnt, const int* __restrict__ c_list,
    const int* __restrict__ e_off, const int* __restrict__ e_cnt,
    const int* __restrict__ e_list, float* __restrict__ gs) {
  __shared__ __align__(16) char smem[SMEM_BYTES];
  unsigned short* P_s  = (unsigned short*)(smem);
  unsigned short* we_s = (unsigned short*)(smem + REGB_OFF);
  unsigned short* wc_s = (unsigned short*)(smem + WC_S_OFF);
  unsigned short* evT  = (unsigned short*)(smem + REGB_OFF);
  unsigned int*   evT32 = (unsigned int*)(smem + REGB_OFF);
  float*          cn_s = (float*)(smem + REGB_OFF);
  int* ev_id = (int*)(smem + MISC_OFF);
  int* cl_id = (int*)(smem + MISC_OFF + 1024);
  float* pp = (float*)(smem + PP_OFF);   // [3][4][128] partial pooled sums

  int g = blockIdx.x >> 2;
  int ds = blockIdx.x & 3;
  int dsbase = ds * DW;
  int t = threadIdx.x, lane = t & 63, w = t >> 6;
  int ln = lane & 15, kb = lane >> 4;

  int ne = min(e_cnt[g], NE_CAP);
  int eoff = e_off[g];
  int nloc = min(c_cnt[g], NCMAX);
  int coff = c_off[g];
  if (nloc <= 0) {
    if (t < 384) {
      int q = t >> 7, d = t & 127;
      gs[(size_t)g * 3 * NHID + q * NHID + dsbase + d] = 0.f;
    }
    return;
  }
  int KT = (ne + 31) >> 5;
  int NT = KT * 2;

  // ---- phase 0: stage ids + we_s + wc_s (raw bf16 copies) ----
  for (int e = t; e < NE_CAP; e += 512)
    ev_id[e] = (e < ne) ? (int)eidx[e_list[eoff + e]] : 0;
  if (t < NCMAX) cl_id[t] = (t < nloc) ? (int)cidx[c_list[coff + t]] : 0;
  {
    int q = t & 7, er = t >> 3;  // 64 rows per pass, 16B per thread
    for (int base_ = 0; base_ < NE_CAP; base_ += 64) {
      int e = base_ + er;
      u16x8 v = (u16x8){0, 0, 0, 0, 0, 0, 0, 0};
      if (e < ne) v = *(const u16x8*)(wep + (size_t)e_list[eoff + e] * PROJ + q * 8);
      *(u16x8*)(we_s + e * WE_S_STRIDE + q * 8) = v;
    }
    for (int base_ = 0; base_ < NCMAX; base_ += 64) {
      int c = base_ + er;
      u16x8 v = (u16x8){0, 0, 0, 0, 0, 0, 0, 0};
      if (c < nloc) v = *(const u16x8*)(wcp + (size_t)c_list[coff + c] * PROJ + q * 8);
      *(u16x8*)(wc_s + c * WE_S_STRIDE + q * 8) = v;
    }
  }
  __syncthreads();

  // ---- score phase: S = wc @ we^T via MFMA ----
  {
    f32x4 sa[16];
#pragma unroll
    for (int i = 0; i < 16; i++) sa[i] = (f32x4){0.f, 0.f, 0.f, 0.f};
    const unsigned short* arow = wc_s + ((w << 4) + ln) * WE_S_STRIDE;
#pragma unroll
    for (int ks = 0; ks < 2; ks++) {
      s16x8 af = *(const s16x8*)(arow + ks * 32 + kb * 8);
#pragma unroll
      for (int nt = 0; nt < 16; nt++) {
        if (nt < NT) {
          s16x8 bf = *(const s16x8*)(we_s + (nt * 16 + ln) * WE_S_STRIDE + ks * 32 + kb * 8);
          sa[nt] = __builtin_amdgcn_mfma_f32_16x16x32_bf16(af, bf, sa[nt], 0, 0, 0);
        }
      }
    }
#pragma unroll
    for (int r = 0; r < 4; r++) {
      int claim = (w << 4) + (kb << 2) + r;
      float mx = -1e30f;
#pragma unroll
      for (int nt = 0; nt < 16; nt++) {
        if (nt < NT) {
          float v = sa[nt][r];
          v = (nt * 16 + ln < ne) ? v : -1e30f;
          sa[nt][r] = v;
          mx = fmaxf(mx, v);
        }
      }
      mx = fmaxf(mx, __shfl_xor(mx, 1));
      mx = fmaxf(mx, __shfl_xor(mx, 2));
      mx = fmaxf(mx, __shfl_xor(mx, 4));
      mx = fmaxf(mx, __shfl_xor(mx, 8));
      float sum = 0.f;
#pragma unroll
      for (int nt = 0; nt < 16; nt++) {
        if (nt < NT) {
          float p = __expf(sa[nt][r] - mx);
          sa[nt][r] = p;
          sum += p;
        }
      }
      sum += __shfl_xor(sum, 1);
      sum += __shfl_xor(sum, 2);
      sum += __shfl_xor(sum, 4);
      sum += __shfl_xor(sum, 8);
      float inv = 1.f / sum;
#pragma unroll
      for (int nt = 0; nt < 16; nt++) {
        if (nt < NT)
          P_s[claim * P_S_STRIDE + nt * 16 + ln] = f2b(sa[nt][r] * inv);
      }
    }
  }
  __syncthreads();

  // ---- stage evT[d][e] bf16 ----
  for (int idx = t; idx < DW * (NE_CAP / 2); idx += 512) {
    int d = idx & (DW - 1);
    int ep = idx >> 7;
    int e0 = ep * 2;
    float f0 = 0.f, f1 = 0.f;
    if (e0 < ne)     f0 = x[(size_t)ev_id[e0] * NHID + dsbase + d];
    if (e0 + 1 < ne) f1 = x[(size_t)ev_id[e0 + 1] * NHID + dsbase + d];
    evT32[d * (P_S_STRIDE / 2) + ep] = (unsigned)f2b(f0) | ((unsigned)f2b(f1) << 16);
  }
  __syncthreads();

  // ---- PV phase ----
  int mw = w >> 1, nw = w & 1;
  int m0 = mw * 32, n0 = nw * 64;
  f32x4 pc[8];
#pragma unroll
  for (int i = 0; i < 8; i++) pc[i] = (f32x4){0.f, 0.f, 0.f, 0.f};
  {
    const unsigned short* prow0 = P_s + (m0 + ln) * P_S_STRIDE + kb * 8;
    const unsigned short* prow1 = prow0 + 16 * P_S_STRIDE;
#pragma unroll
    for (int kt = 0; kt < 8; kt++) {
      if (kt < KT) {
        int k0 = kt * 32;
        s16x8 a0 = *(const s16x8*)(prow0 + k0);
        s16x8 a1 = *(const s16x8*)(prow1 + k0);
#pragma unroll
        for (int nt = 0; nt < 4; nt++) {
          s16x8 bf = *(const s16x8*)(evT + (n0 + nt * 16 + ln) * P_S_STRIDE + k0 + kb * 8);
          pc[nt]     = __builtin_amdgcn_mfma_f32_16x16x32_bf16(a0, bf, pc[nt], 0, 0, 0);
          pc[4 + nt] = __builtin_amdgcn_mfma_f32_16x16x32_bf16(a1, bf, pc[4 + nt], 0, 0, 0);
        }
      }
    }
  }
  __syncthreads();

  // ---- dump cn to LDS ----
#pragma unroll
  for (int mi = 0; mi < 2; mi++) {
#pragma unroll
    for (int nt = 0; nt < 4; nt++) {
      f32x4 v = pc[mi * 4 + nt];
#pragma unroll
      for (int r = 0; r < 4; r++)
        cn_s[(m0 + mi * 16 + (kb << 2) + r) * CN_S_STRIDE + n0 + nt * 16 + ln] = v[r];
    }
  }
  __syncthreads();

  // ---- pooled sums: LDS partials, block-reduce, plain store ----
  {
    int d = t & (DW - 1);
    int mg = t >> 7;
    float scl = 0.f, scn = 0.f, spr = 0.f;
    for (int m = mg; m < nloc; m += 4) {
      float cl = x[(size_t)cl_id[m] * NHID + dsbase + d];
      float cn = cn_s[m * CN_S_STRIDE + d];
      scl += cl; scn += cn; spr += cl * cn;
    }
    pp[mg * 128 + d] = scl;
    pp[512 + mg * 128 + d] = scn;
    pp[1024 + mg * 128 + d] = spr;
  }
  __syncthreads();
  if (t < 384) {
    int q = t >> 7, d = t & 127;
    const float* base_ = pp + q * 512;
    float v = base_[d] + base_[128 + d] + base_[256 + d] + base_[384 + d];
    gs[(size_t)g * 3 * NHID + q * NHID + dsbase + d] = v;
  }
}

// ---------------- k_mean: mc_bf[g][2048] = mean-concat (bf16) ----------------
__global__ __launch_bounds__(512) void k_mean(const float* __restrict__ gs,
                                              const int* __restrict__ c_cnt,
                                              unsigned short* __restrict__ mc) {
  int g = blockIdx.x, t = threadIdx.x;
  const float* gsg = gs + (size_t)g * 3 * NHID;
  float inv = 1.f / (float)max(c_cnt[g], 1);
  float sc = gsg[t], sn = gsg[NHID + t], sp = gsg[2 * NHID + t];
  unsigned short* m = mc + (size_t)g * 4 * NHID;
  m[t] = f2b(sc * inv);
  m[NHID + t] = f2b(sn * inv);
  m[2 * NHID + t] = f2b((sc - sn) * inv);
  m[3 * NHID + t] = f2b(sp * inv);
}

// ---------------- k_out: out = mc @ Wa + ba via MFMA, full K, no atomics ----------------
__global__ __launch_bounds__(256) void k_out(
    const unsigned short* __restrict__ mc, const unsigned short* __restrict__ WaT,
    const float* __restrict__ ba, float* __restrict__ out) {
  int n0 = blockIdx.x * 64;
  int t = threadIdx.x, lane = t & 63, w = t >> 6;
  int ln = lane & 15, kb = lane >> 4;
  f32x4 acc[4];
#pragma unroll
  for (int nt = 0; nt < 4; nt++) acc[nt] = (f32x4){0.f, 0.f, 0.f, 0.f};
  const unsigned short* arow = mc + (size_t)(w * 16 + ln) * (4 * NHID);
#pragma unroll 4
  for (int kt = 0; kt < 64; kt++) {
    int k0 = kt * 32 + kb * 8;
    s16x8 af = *(const s16x8*)(arow + k0);
#pragma unroll
    for (int nt = 0; nt < 4; nt++) {
      s16x8 bf = *(const s16x8*)(WaT + (size_t)(n0 + nt * 16 + ln) * (4 * NHID) + k0);
      acc[nt] = __builtin_amdgcn_mfma_f32_16x16x32_bf16(af, bf, acc[nt], 0, 0, 0);
    }
  }
#pragma unroll
  for (int nt = 0; nt < 4; nt++)
#pragma unroll
    for (int r = 0; r < 4; r++) {
      int gg = w * 16 + kb * 4 + r;
      int col = n0 + nt * 16 + ln;
      out[(size_t)gg * NHID + col] = acc[nt][r] + ba[col];
    }
}

extern "C" void kernel_launch(void* const* d_in, const int* in_sizes, int n_in,
                              void* d_out, int out_size, void* d_ws, size_t ws_size,
                              hipStream_t stream) {
  const float* x = (const float*)d_in[0];
  const int* batch = (const int*)d_in[1];
  const int* cidx = (const int*)d_in[2];
  const int* eidx = (const int*)d_in[3];
  const float* Wc = (const float*)d_in[4];
  const float* bc = (const float*)d_in[5];
  const float* We = (const float*)d_in[6];
  const float* be = (const float*)d_in[7];
  const float* Wa = (const float*)d_in[8];
  const float* ba = (const float*)d_in[9];
  float* out = (float*)d_out;

  char* w = (char*)d_ws;
  int* cb = (int*)w;      w += NC * 4;
  int* eb = (int*)w;      w += NEV * 4;
  int* c_off = (int*)w;   w += NG * 4;
  int* c_cnt = (int*)w;   w += NG * 4;
  int* e_off = (int*)w;   w += NG * 4;
  int* e_cnt = (int*)w;   w += NG * 4;
  int* c_list = (int*)w;  w += NC * 4;
  int* e_list = (int*)w;  w += NEV * 4;
  unsigned short* wcp = (unsigned short*)w; w += (size_t)NC * PROJ * 2;
  unsigned short* wep = (unsigned short*)w; w += (size_t)NEV * PROJ * 2;
  unsigned short* WcT = (unsigned short*)w; w += (size_t)PROJ * NHID * 2;
  unsigned short* WeT = (unsigned short*)w; w += (size_t)PROJ * NHID * 2;
  unsigned short* WaT = (unsigned short*)w; w += (size_t)NHID * 4 * NHID * 2;
  unsigned short* mcb = (unsigned short*)w; w += (size_t)NG * 4 * NHID * 2;
  float* gs = (float*)w;  w += (size_t)NG * 3 * NHID * 4;

  k_pre<<<(NC + NEV) / 256, 256, 0, stream>>>(batch, cidx, eidx, cb, eb);
  k_compact<<<NG, 256, 0, stream>>>(cb, eb, c_off, c_cnt, c_list, e_off, e_cnt, e_list);
  k_t64<<<16 + 256, 256, 0, stream>>>(Wc, We, Wa, WcT, WeT, WaT);
  k_proj<<<(NC + NEV) / 64, 128, 0, stream>>>(x, cidx, eidx, WcT, WeT, bc, be, wcp, wep);
  k_attn<<<NG * DSLICES, 512, 0, stream>>>(x, cidx, eidx, wcp, wep, c_off, c_cnt,
                                           c_list, e_off, e_cnt, e_list, gs);
  k_mean<<<NG, 512, 0, stream>>>(gs, c_cnt, mcb);
  k_out<<<8, 256, 0, stream>>>(mcb, WaT, ba, out);
}

// Round 5
// 95.397 us; speedup vs baseline: 1.2701x; 1.2701x over previous
//
#include <hip/hip_runtime.h>
#include <hip/hip_bf16.h>

#define NHID 512
#define PROJ 64
#define NC 4096
#define NEV 8192
#define NG 64
#define NCMAX 128
#define NE_CAP 256
#define DSLICES 4
#define DW 128

typedef __attribute__((ext_vector_type(8))) short s16x8;
typedef __attribute__((ext_vector_type(8))) unsigned short u16x8;
typedef __attribute__((ext_vector_type(4))) float f32x4;

// ---- k_attn LDS layout (bytes) ----
#define P_S_STRIDE 264            // bf16 elems per row (256 + 8 pad), 528B
#define P_S_BYTES  (NCMAX * P_S_STRIDE * 2)        // 67584
#define REGB_OFF   P_S_BYTES
#define WE_S_STRIDE 72            // bf16 elems (64 + 8 pad), 144B
#define WC_S_OFF   (REGB_OFF + NE_CAP * WE_S_STRIDE * 2)
#define CN_S_STRIDE 132           // f32 elems per row
#define MISC_OFF   (REGB_OFF + P_S_BYTES)
#define PP_OFF     (MISC_OFF + 1536)               // 3*4*128 floats = 6144B
#define SMEM_BYTES (PP_OFF + 6144)

static __device__ __forceinline__ unsigned short f2b(float f) {
  union { __hip_bfloat16 h; unsigned short u; } v;
  v.h = __float2bfloat16(f);
  return v.u;
}

// ---------------- compact_scan: stable compaction, 2 barriers total ----------------
// thread t owns contiguous range [t*NPT, (t+1)*NPT); stable order preserved.
template <int NPT>
__device__ __forceinline__ void compact_scan(
    const int* __restrict__ batch, const int* __restrict__ idx, int g,
    int* __restrict__ off_out, int* __restrict__ cnt_out, int* __restrict__ list,
    int* wtot, int* wless) {
  int t = threadIdx.x, lane = t & 63, w = t >> 6;
  int vals[NPT];
  int base_i = t * NPT;
  int eq = 0, less = 0;
#pragma unroll
  for (int j = 0; j < NPT; j++) {
    int v = batch[idx[base_i + j]];
    vals[j] = v;
    eq += (v == g) ? 1 : 0;
    less += (v < g) ? 1 : 0;
  }
  // wave inclusive scan of eq
  int s = eq;
#pragma unroll
  for (int off = 1; off < 64; off <<= 1) {
    int o = __shfl_up(s, off);
    if (lane >= off) s += o;
  }
  // wave reduce of less
  int ls = less;
#pragma unroll
  for (int off = 32; off; off >>= 1) ls += __shfl_xor(ls, off);
  if (lane == 63) wtot[w] = s;
  if (lane == 0) wless[w] = ls;
  __syncthreads();
  int wbase = 0;
#pragma unroll
  for (int k = 0; k < 4; k++)
    if (k < w) wbase += wtot[k];
  int base = wless[0] + wless[1] + wless[2] + wless[3];
  int pos = base + wbase + (s - eq);
#pragma unroll
  for (int j = 0; j < NPT; j++) {
    if (vals[j] == g) list[pos++] = base_i + j;
  }
  if (t == 255) {
    cnt_out[g] = wbase + s;
    off_out[g] = base;
  }
  __syncthreads();  // protect wtot/wless for next call
}

// ---------------- k_front: compaction (blocks 0..63) + weight transposes (blocks 64..335) ----------------
__global__ __launch_bounds__(256) void k_front(
    const float* __restrict__ Wc, const float* __restrict__ We,
    const float* __restrict__ Wa, unsigned short* __restrict__ WcT,
    unsigned short* __restrict__ WeT, unsigned short* __restrict__ WaT,
    const int* __restrict__ batch, const int* __restrict__ cidx,
    const int* __restrict__ eidx, int* __restrict__ c_off, int* __restrict__ c_cnt,
    int* __restrict__ c_list, int* __restrict__ e_off, int* __restrict__ e_cnt,
    int* __restrict__ e_list) {
  __shared__ __align__(16) char sm[64 * 65 * 4];
  int b = blockIdx.x;
  if (b < NG) {
    int* wtot = (int*)sm;
    int* wless = ((int*)sm) + 4;
    compact_scan<NC / 256>(batch, cidx, b, c_off, c_cnt, c_list, wtot, wless);
    compact_scan<NEV / 256>(batch, eidx, b, e_off, e_cnt, e_list, wtot, wless);
    return;
  }
  int tb = b - NG;
  float(*ts)[65] = (float(*)[65])sm;
  const float* src; unsigned short* dst; int K, N, kt, nt;
  if (tb < 8)       { src = Wc; dst = WcT; K = 512;  N = 64;  kt = tb;           nt = 0; }
  else if (tb < 16) { src = We; dst = WeT; K = 512;  N = 64;  kt = tb - 8;       nt = 0; }
  else              { src = Wa; dst = WaT; K = 2048; N = 512; kt = (tb - 16) >> 3; nt = (tb - 16) & 7; }
  int k0 = kt * 64, n0 = nt * 64;
  int t = threadIdx.x;
  int c = t & 63, r0 = t >> 6;
#pragma unroll
  for (int p = 0; p < 16; p++) {
    int r = r0 * 16 + p;
    ts[r][c] = src[(size_t)(k0 + r) * N + n0 + c];
  }
  __syncthreads();
  int n = t >> 2, q = t & 3;
  unsigned short tmp[16];
#pragma unroll
  for (int j = 0; j < 16; j++) tmp[j] = f2b(ts[q * 16 + j][n]);
  u16x8* dp = (u16x8*)(dst + (size_t)(n0 + n) * K + k0 + q * 16);
  dp[0] = *(u16x8*)tmp;
  dp[1] = *(u16x8*)(tmp + 8);
}

// ---------------- k_proj: MFMA GEMM, no LDS; out = bf16 ----------------
__global__ __launch_bounds__(128) void k_proj(
    const float* __restrict__ x, const int* __restrict__ cidx,
    const int* __restrict__ eidx, const unsigned short* __restrict__ WcT,
    const unsigned short* __restrict__ WeT, const float* __restrict__ bc,
    const float* __restrict__ be, unsigned short* __restrict__ wcp,
    unsigned short* __restrict__ wep) {
  int b = blockIdx.x;
  const int* idx; const unsigned short* WT; const float* bias;
  unsigned short* out; int base;
  if (b < NC / 64) { idx = cidx; WT = WcT; bias = bc; out = wcp; base = b * 64; }
  else             { idx = eidx; WT = WeT; bias = be; out = wep; base = (b - NC / 64) * 64; }
  int t = threadIdx.x, lane = t & 63, w = t >> 6;
  int ln = lane & 15, kb = lane >> 4;
  int m0 = w * 32;
  const float* xr0 = x + (size_t)idx[base + m0 + ln] * NHID;
  const float* xr1 = x + (size_t)idx[base + m0 + 16 + ln] * NHID;
  float bv[4];
#pragma unroll
  for (int nt = 0; nt < 4; nt++) bv[nt] = bias[nt * 16 + ln];
  f32x4 acc[2][4];
#pragma unroll
  for (int mi = 0; mi < 2; mi++)
#pragma unroll
    for (int nt = 0; nt < 4; nt++) acc[mi][nt] = (f32x4){0.f, 0.f, 0.f, 0.f};

#pragma unroll
  for (int kt = 0; kt < 8; kt++) {
#pragma unroll
    for (int ks = 0; ks < 2; ks++) {
      int k0 = kt * 64 + ks * 32 + kb * 8;
      float4 p0 = *(const float4*)(xr0 + k0);
      float4 p1 = *(const float4*)(xr0 + k0 + 4);
      float4 q0 = *(const float4*)(xr1 + k0);
      float4 q1 = *(const float4*)(xr1 + k0 + 4);
      s16x8 a0, a1;
      a0[0] = (short)f2b(p0.x); a0[1] = (short)f2b(p0.y);
      a0[2] = (short)f2b(p0.z); a0[3] = (short)f2b(p0.w);
      a0[4] = (short)f2b(p1.x); a0[5] = (short)f2b(p1.y);
      a0[6] = (short)f2b(p1.z); a0[7] = (short)f2b(p1.w);
      a1[0] = (short)f2b(q0.x); a1[1] = (short)f2b(q0.y);
      a1[2] = (short)f2b(q0.z); a1[3] = (short)f2b(q0.w);
      a1[4] = (short)f2b(q1.x); a1[5] = (short)f2b(q1.y);
      a1[6] = (short)f2b(q1.z); a1[7] = (short)f2b(q1.w);
#pragma unroll
      for (int nt = 0; nt < 4; nt++) {
        s16x8 bf = *(const s16x8*)(WT + (size_t)(nt * 16 + ln) * NHID + k0);
        acc[0][nt] = __builtin_amdgcn_mfma_f32_16x16x32_bf16(a0, bf, acc[0][nt], 0, 0, 0);
        acc[1][nt] = __builtin_amdgcn_mfma_f32_16x16x32_bf16(a1, bf, acc[1][nt], 0, 0, 0);
      }
    }
  }
#pragma unroll
  for (int mi = 0; mi < 2; mi++)
#pragma unroll
    for (int nt = 0; nt < 4; nt++)
#pragma unroll
      for (int r = 0; r < 4; r++) {
        int rowg = base + m0 + mi * 16 + kb * 4 + r;
        out[(size_t)rowg * PROJ + nt * 16 + ln] = f2b(acc[mi][nt][r] + bv[nt]);
      }
}

// ---------------- k_attn: MFMA attention + fused mean-concat epilogue ----------------
__global__ __launch_bounds__(512) void k_attn(
    const float* __restrict__ x, const int* __restrict__ cidx,
    const int* __restrict__ eidx, const unsigned short* __restrict__ wcp,
    const unsigned short* __restrict__ wep, const int* __restrict__ c_off,
    const int* __restrict__ c_cnt, const int* __restrict__ c_list,
    const int* __restrict__ e_off, const int* __restrict__ e_cnt,
    const int* __restrict__ e_list, unsigned short* __restrict__ mcb) {
  __shared__ __align__(16) char smem[SMEM_BYTES];
  unsigned short* P_s  = (unsigned short*)(smem);
  unsigned short* we_s = (unsigned short*)(smem + REGB_OFF);
  unsigned short* wc_s = (unsigned short*)(smem + WC_S_OFF);
  unsigned short* evT  = (unsigned short*)(smem + REGB_OFF);
  unsigned int*   evT32 = (unsigned int*)(smem + REGB_OFF);
  float*          cn_s = (float*)(smem + REGB_OFF);
  int* ev_id = (int*)(smem + MISC_OFF);
  int* cl_id = (int*)(smem + MISC_OFF + 1024);
  float* pp = (float*)(smem + PP_OFF);   // [3][4][128] partial pooled sums

  int g = blockIdx.x >> 2;
  int ds = blockIdx.x & 3;
  int dsbase = ds * DW;
  int t = threadIdx.x, lane = t & 63, w = t >> 6;
  int ln = lane & 15, kb = lane >> 4;

  int ne = min(e_cnt[g], NE_CAP);
  int eoff = e_off[g];
  int ccnt_full = c_cnt[g];
  int nloc = min(ccnt_full, NCMAX);
  int coff = c_off[g];
  if (nloc <= 0) {
    int q = t >> 7, d = t & 127;
    mcb[(size_t)g * 4 * NHID + q * NHID + dsbase + d] = 0;
    return;
  }
  int KT = (ne + 31) >> 5;
  int NT = KT * 2;

  // ---- phase 0: stage ids + we_s + wc_s (raw bf16 copies) ----
  for (int e = t; e < NE_CAP; e += 512)
    ev_id[e] = (e < ne) ? (int)eidx[e_list[eoff + e]] : 0;
  if (t < NCMAX) cl_id[t] = (t < nloc) ? (int)cidx[c_list[coff + t]] : 0;
  {
    int q = t & 7, er = t >> 3;  // 64 rows per pass, 16B per thread
    for (int base_ = 0; base_ < NE_CAP; base_ += 64) {
      int e = base_ + er;
      u16x8 v = (u16x8){0, 0, 0, 0, 0, 0, 0, 0};
      if (e < ne) v = *(const u16x8*)(wep + (size_t)e_list[eoff + e] * PROJ + q * 8);
      *(u16x8*)(we_s + e * WE_S_STRIDE + q * 8) = v;
    }
    for (int base_ = 0; base_ < NCMAX; base_ += 64) {
      int c = base_ + er;
      u16x8 v = (u16x8){0, 0, 0, 0, 0, 0, 0, 0};
      if (c < nloc) v = *(const u16x8*)(wcp + (size_t)c_list[coff + c] * PROJ + q * 8);
      *(u16x8*)(wc_s + c * WE_S_STRIDE + q * 8) = v;
    }
  }
  __syncthreads();

  // ---- score phase: S = wc @ we^T via MFMA ----
  {
    f32x4 sa[16];
#pragma unroll
    for (int i = 0; i < 16; i++) sa[i] = (f32x4){0.f, 0.f, 0.f, 0.f};
    const unsigned short* arow = wc_s + ((w << 4) + ln) * WE_S_STRIDE;
#pragma unroll
    for (int ks = 0; ks < 2; ks++) {
      s16x8 af = *(const s16x8*)(arow + ks * 32 + kb * 8);
#pragma unroll
      for (int nt = 0; nt < 16; nt++) {
        if (nt < NT) {
          s16x8 bf = *(const s16x8*)(we_s + (nt * 16 + ln) * WE_S_STRIDE + ks * 32 + kb * 8);
          sa[nt] = __builtin_amdgcn_mfma_f32_16x16x32_bf16(af, bf, sa[nt], 0, 0, 0);
        }
      }
    }
#pragma unroll
    for (int r = 0; r < 4; r++) {
      int claim = (w << 4) + (kb << 2) + r;
      float mx = -1e30f;
#pragma unroll
      for (int nt = 0; nt < 16; nt++) {
        if (nt < NT) {
          float v = sa[nt][r];
          v = (nt * 16 + ln < ne) ? v : -1e30f;
          sa[nt][r] = v;
          mx = fmaxf(mx, v);
        }
      }
      mx = fmaxf(mx, __shfl_xor(mx, 1));
      mx = fmaxf(mx, __shfl_xor(mx, 2));
      mx = fmaxf(mx, __shfl_xor(mx, 4));
      mx = fmaxf(mx, __shfl_xor(mx, 8));
      float sum = 0.f;
#pragma unroll
      for (int nt = 0; nt < 16; nt++) {
        if (nt < NT) {
          float p = __expf(sa[nt][r] - mx);
          sa[nt][r] = p;
          sum += p;
        }
      }
      sum += __shfl_xor(sum, 1);
      sum += __shfl_xor(sum, 2);
      sum += __shfl_xor(sum, 4);
      sum += __shfl_xor(sum, 8);
      float inv = 1.f / sum;
#pragma unroll
      for (int nt = 0; nt < 16; nt++) {
        if (nt < NT)
          P_s[claim * P_S_STRIDE + nt * 16 + ln] = f2b(sa[nt][r] * inv);
      }
    }
  }
  __syncthreads();

  // ---- stage evT[d][e] bf16 ----
  for (int idx = t; idx < DW * (NE_CAP / 2); idx += 512) {
    int d = idx & (DW - 1);
    int ep = idx >> 7;
    int e0 = ep * 2;
    float f0 = 0.f, f1 = 0.f;
    if (e0 < ne)     f0 = x[(size_t)ev_id[e0] * NHID + dsbase + d];
    if (e0 + 1 < ne) f1 = x[(size_t)ev_id[e0 + 1] * NHID + dsbase + d];
    evT32[d * (P_S_STRIDE / 2) + ep] = (unsigned)f2b(f0) | ((unsigned)f2b(f1) << 16);
  }
  __syncthreads();

  // ---- PV phase ----
  int mw = w >> 1, nw = w & 1;
  int m0 = mw * 32, n0 = nw * 64;
  f32x4 pc[8];
#pragma unroll
  for (int i = 0; i < 8; i++) pc[i] = (f32x4){0.f, 0.f, 0.f, 0.f};
  {
    const unsigned short* prow0 = P_s + (m0 + ln) * P_S_STRIDE + kb * 8;
    const unsigned short* prow1 = prow0 + 16 * P_S_STRIDE;
#pragma unroll
    for (int kt = 0; kt < 8; kt++) {
      if (kt < KT) {
        int k0 = kt * 32;
        s16x8 a0 = *(const s16x8*)(prow0 + k0);
        s16x8 a1 = *(const s16x8*)(prow1 + k0);
#pragma unroll
        for (int nt = 0; nt < 4; nt++) {
          s16x8 bf = *(const s16x8*)(evT + (n0 + nt * 16 + ln) * P_S_STRIDE + k0 + kb * 8);
          pc[nt]     = __builtin_amdgcn_mfma_f32_16x16x32_bf16(a0, bf, pc[nt], 0, 0, 0);
          pc[4 + nt] = __builtin_amdgcn_mfma_f32_16x16x32_bf16(a1, bf, pc[4 + nt], 0, 0, 0);
        }
      }
    }
  }
  __syncthreads();

  // ---- dump cn to LDS ----
#pragma unroll
  for (int mi = 0; mi < 2; mi++) {
#pragma unroll
    for (int nt = 0; nt < 4; nt++) {
      f32x4 v = pc[mi * 4 + nt];
#pragma unroll
      for (int r = 0; r < 4; r++)
        cn_s[(m0 + mi * 16 + (kb << 2) + r) * CN_S_STRIDE + n0 + nt * 16 + ln] = v[r];
    }
  }
  __syncthreads();

  // ---- pooled sums: LDS partials ----
  {
    int d = t & (DW - 1);
    int mg = t >> 7;
    float scl = 0.f, scn = 0.f, spr = 0.f;
    for (int m = mg; m < nloc; m += 4) {
      float cl = x[(size_t)cl_id[m] * NHID + dsbase + d];
      float cn = cn_s[m * CN_S_STRIDE + d];
      scl += cl; scn += cn; spr += cl * cn;
    }
    pp[mg * 128 + d] = scl;
    pp[512 + mg * 128 + d] = scn;
    pp[1024 + mg * 128 + d] = spr;
  }
  __syncthreads();

  // ---- fused mean-concat epilogue: write mcb quadrants (bf16) ----
  {
    int q = t >> 7, d = t & 127;
    float s0 = pp[d] + pp[128 + d] + pp[256 + d] + pp[384 + d];
    float s1 = pp[512 + d] + pp[640 + d] + pp[768 + d] + pp[896 + d];
    float s2 = pp[1024 + d] + pp[1152 + d] + pp[1280 + d] + pp[1408 + d];
    float inv = 1.f / (float)max(ccnt_full, 1);
    float v = (q == 0) ? s0 : (q == 1) ? s1 : (q == 2) ? (s0 - s1) : s2;
    mcb[(size_t)g * 4 * NHID + q * NHID + dsbase + d] = f2b(v * inv);
  }
}

// ---------------- k_out: out = mc @ Wa + ba via MFMA, 2-way K-split in-block ----------------
__global__ __launch_bounds__(512) void k_out(
    const unsigned short* __restrict__ mc, const unsigned short* __restrict__ WaT,
    const float* __restrict__ ba, float* __restrict__ out) {
  __shared__ float red[2][64][64];   // kh x row x col = 32KB
  int n0 = blockIdx.x * 64;
  int t = threadIdx.x, lane = t & 63, wv = t >> 6;
  int mh = wv & 3, kh = wv >> 2;
  int ln = lane & 15, kb = lane >> 4;
  f32x4 acc[4];
#pragma unroll
  for (int nt = 0; nt < 4; nt++) acc[nt] = (f32x4){0.f, 0.f, 0.f, 0.f};
  const unsigned short* arow = mc + (size_t)(mh * 16 + ln) * (4 * NHID);
#pragma unroll 4
  for (int kt = kh * 32; kt < kh * 32 + 32; kt++) {
    int k0 = kt * 32 + kb * 8;
    s16x8 af = *(const s16x8*)(arow + k0);
#pragma unroll
    for (int nt = 0; nt < 4; nt++) {
      s16x8 bf = *(const s16x8*)(WaT + (size_t)(n0 + nt * 16 + ln) * (4 * NHID) + k0);
      acc[nt] = __builtin_amdgcn_mfma_f32_16x16x32_bf16(af, bf, acc[nt], 0, 0, 0);
    }
  }
#pragma unroll
  for (int nt = 0; nt < 4; nt++)
#pragma unroll
    for (int r = 0; r < 4; r++)
      red[kh][mh * 16 + kb * 4 + r][nt * 16 + ln] = acc[nt][r];
  __syncthreads();
  for (int i = t; i < 4096; i += 512) {
    int row = i >> 6, col = i & 63;
    out[(size_t)row * NHID + n0 + col] = red[0][row][col] + red[1][row][col] + ba[n0 + col];
  }
}

extern "C" void kernel_launch(void* const* d_in, const int* in_sizes, int n_in,
                              void* d_out, int out_size, void* d_ws, size_t ws_size,
                              hipStream_t stream) {
  const float* x = (const float*)d_in[0];
  const int* batch = (const int*)d_in[1];
  const int* cidx = (const int*)d_in[2];
  const int* eidx = (const int*)d_in[3];
  const float* Wc = (const float*)d_in[4];
  const float* bc = (const float*)d_in[5];
  const float* We = (const float*)d_in[6];
  const float* be = (const float*)d_in[7];
  const float* Wa = (const float*)d_in[8];
  const float* ba = (const float*)d_in[9];
  float* out = (float*)d_out;

  char* w = (char*)d_ws;
  int* c_off = (int*)w;   w += NG * 4;
  int* c_cnt = (int*)w;   w += NG * 4;
  int* e_off = (int*)w;   w += NG * 4;
  int* e_cnt = (int*)w;   w += NG * 4;
  int* c_list = (int*)w;  w += NC * 4;
  int* e_list = (int*)w;  w += NEV * 4;
  unsigned short* wcp = (unsigned short*)w; w += (size_t)NC * PROJ * 2;
  unsigned short* wep = (unsigned short*)w; w += (size_t)NEV * PROJ * 2;
  unsigned short* WcT = (unsigned short*)w; w += (size_t)PROJ * NHID * 2;
  unsigned short* WeT = (unsigned short*)w; w += (size_t)PROJ * NHID * 2;
  unsigned short* WaT = (unsigned short*)w; w += (size_t)NHID * 4 * NHID * 2;
  unsigned short* mcb = (unsigned short*)w; w += (size_t)NG * 4 * NHID * 2;

  k_front<<<NG + 16 + 256, 256, 0, stream>>>(Wc, We, Wa, WcT, WeT, WaT, batch, cidx,
                                             eidx, c_off, c_cnt, c_list, e_off, e_cnt,
                                             e_list);
  k_proj<<<(NC + NEV) / 64, 128, 0, stream>>>(x, cidx, eidx, WcT, WeT, bc, be, wcp, wep);
  k_attn<<<NG * DSLICES, 512, 0, stream>>>(x, cidx, eidx, wcp, wep, c_off, c_cnt,
                                           c_list, e_off, e_cnt, e_list, mcb);
  k_out<<<8, 512, 0, stream>>>(mcb, WaT, ba, out);
}

// Round 6
// 72.771 us; speedup vs baseline: 1.6650x; 1.3109x over previous
//
#include <hip/hip_runtime.h>
#include <hip/hip_bf16.h>

#define NHID 512
#define PROJ 64
#define NC 4096
#define NEV 8192
#define NG 64
#define NCMAX 128
#define NE_CAP 256
#define DSLICES 4
#define DW 128

typedef __attribute__((ext_vector_type(8))) short s16x8;
typedef __attribute__((ext_vector_type(8))) unsigned short u16x8;
typedef __attribute__((ext_vector_type(4))) float f32x4;

// ---- k_attn LDS layout (bytes) ----
#define P_S_STRIDE 264            // bf16 elems per row (256 + 8 pad), 528B
#define P_S_BYTES  (NCMAX * P_S_STRIDE * 2)        // 67584
#define REGB_OFF   P_S_BYTES
#define WE_S_STRIDE 72            // bf16 elems (64 + 8 pad), 144B
#define WC_S_OFF   (REGB_OFF + NE_CAP * WE_S_STRIDE * 2)
#define CN_S_STRIDE 132           // f32 elems per row
#define MISC_OFF   (REGB_OFF + P_S_BYTES)
#define SMEM_BYTES (MISC_OFF + 1536)

static __device__ __forceinline__ unsigned short f2b(float f) {
  union { __hip_bfloat16 h; unsigned short u; } v;
  v.h = __float2bfloat16(f);
  return v.u;
}

// ---------------- compact_scan: stable compaction, 2 barriers total ----------------
template <int NPT>
__device__ __forceinline__ void compact_scan(
    const int* __restrict__ batch, const int* __restrict__ idx, int g,
    int* __restrict__ off_out, int* __restrict__ cnt_out, int* __restrict__ list,
    int* wtot, int* wless) {
  int t = threadIdx.x, lane = t & 63, w = t >> 6;
  int vals[NPT];
  int base_i = t * NPT;
  int eq = 0, less = 0;
#pragma unroll
  for (int j = 0; j < NPT; j++) {
    int v = batch[idx[base_i + j]];
    vals[j] = v;
    eq += (v == g) ? 1 : 0;
    less += (v < g) ? 1 : 0;
  }
  int s = eq;
#pragma unroll
  for (int off = 1; off < 64; off <<= 1) {
    int o = __shfl_up(s, off);
    if (lane >= off) s += o;
  }
  int ls = less;
#pragma unroll
  for (int off = 32; off; off >>= 1) ls += __shfl_xor(ls, off);
  if (lane == 63) wtot[w] = s;
  if (lane == 0) wless[w] = ls;
  __syncthreads();
  int wbase = 0;
#pragma unroll
  for (int k = 0; k < 4; k++)
    if (k < w) wbase += wtot[k];
  int base = wless[0] + wless[1] + wless[2] + wless[3];
  int pos = base + wbase + (s - eq);
#pragma unroll
  for (int j = 0; j < NPT; j++) {
    if (vals[j] == g) list[pos++] = base_i + j;
  }
  if (t == 255) {
    cnt_out[g] = wbase + s;
    off_out[g] = base;
  }
  __syncthreads();
}

// ---------------- k_front: compaction (blocks 0..63) + weight transposes ----------------
__global__ __launch_bounds__(256) void k_front(
    const float* __restrict__ Wc, const float* __restrict__ We,
    const float* __restrict__ Wa, unsigned short* __restrict__ WcT,
    unsigned short* __restrict__ WeT, unsigned short* __restrict__ WaT,
    const int* __restrict__ batch, const int* __restrict__ cidx,
    const int* __restrict__ eidx, int* __restrict__ c_off, int* __restrict__ c_cnt,
    int* __restrict__ c_list, int* __restrict__ e_off, int* __restrict__ e_cnt,
    int* __restrict__ e_list) {
  __shared__ __align__(16) char sm[64 * 65 * 4];
  int b = blockIdx.x;
  if (b < NG) {
    int* wtot = (int*)sm;
    int* wless = ((int*)sm) + 4;
    compact_scan<NC / 256>(batch, cidx, b, c_off, c_cnt, c_list, wtot, wless);
    compact_scan<NEV / 256>(batch, eidx, b, e_off, e_cnt, e_list, wtot, wless);
    return;
  }
  int tb = b - NG;
  float(*ts)[65] = (float(*)[65])sm;
  const float* src; unsigned short* dst; int K, N, kt, nt;
  if (tb < 8)       { src = Wc; dst = WcT; K = 512;  N = 64;  kt = tb;           nt = 0; }
  else if (tb < 16) { src = We; dst = WeT; K = 512;  N = 64;  kt = tb - 8;       nt = 0; }
  else              { src = Wa; dst = WaT; K = 2048; N = 512; kt = (tb - 16) >> 3; nt = (tb - 16) & 7; }
  int k0 = tb >= 16 ? kt * 64 : kt * 64, n0 = nt * 64;
  int t = threadIdx.x;
  int c = t & 63, r0 = t >> 6;
#pragma unroll
  for (int p = 0; p < 16; p++) {
    int r = r0 * 16 + p;
    ts[r][c] = src[(size_t)(k0 + r) * N + n0 + c];
  }
  __syncthreads();
  int n = t >> 2, q = t & 3;
  unsigned short tmp[16];
#pragma unroll
  for (int j = 0; j < 16; j++) tmp[j] = f2b(ts[q * 16 + j][n]);
  u16x8* dp = (u16x8*)(dst + (size_t)(n0 + n) * K + k0 + q * 16);
  dp[0] = *(u16x8*)tmp;
  dp[1] = *(u16x8*)(tmp + 8);
}

// ---------------- k_proj: MFMA GEMM, 2-way K-split, 4 waves/block ----------------
__global__ __launch_bounds__(256) void k_proj(
    const float* __restrict__ x, const int* __restrict__ cidx,
    const int* __restrict__ eidx, const unsigned short* __restrict__ WcT,
    const unsigned short* __restrict__ WeT, const float* __restrict__ bc,
    const float* __restrict__ be, unsigned short* __restrict__ wcp,
    unsigned short* __restrict__ wep) {
  __shared__ float red[2][2][16][64];   // [kh][mh][row][col] = 16KB
  int b = blockIdx.x;
  const int* idx; const unsigned short* WT; const float* bias;
  unsigned short* out; int base;
  if (b < NC / 32) { idx = cidx; WT = WcT; bias = bc; out = wcp; base = b * 32; }
  else             { idx = eidx; WT = WeT; bias = be; out = wep; base = (b - NC / 32) * 32; }
  int t = threadIdx.x, lane = t & 63, w = t >> 6;
  int mh = w & 1, kh = w >> 1;
  int ln = lane & 15, kb = lane >> 4;
  const float* xr = x + (size_t)idx[base + mh * 16 + ln] * NHID + kh * 256;
  const unsigned short* wb = WT + kh * 256;
  f32x4 acc[4];
#pragma unroll
  for (int nt = 0; nt < 4; nt++) acc[nt] = (f32x4){0.f, 0.f, 0.f, 0.f};
#pragma unroll
  for (int kt = 0; kt < 8; kt++) {
    int k0 = kt * 32 + kb * 8;
    float4 p0 = *(const float4*)(xr + k0);
    float4 p1 = *(const float4*)(xr + k0 + 4);
    s16x8 a;
    a[0] = (short)f2b(p0.x); a[1] = (short)f2b(p0.y);
    a[2] = (short)f2b(p0.z); a[3] = (short)f2b(p0.w);
    a[4] = (short)f2b(p1.x); a[5] = (short)f2b(p1.y);
    a[6] = (short)f2b(p1.z); a[7] = (short)f2b(p1.w);
#pragma unroll
    for (int nt = 0; nt < 4; nt++) {
      s16x8 bf = *(const s16x8*)(wb + (size_t)(nt * 16 + ln) * NHID + k0);
      acc[nt] = __builtin_amdgcn_mfma_f32_16x16x32_bf16(a, bf, acc[nt], 0, 0, 0);
    }
  }
#pragma unroll
  for (int nt = 0; nt < 4; nt++)
#pragma unroll
    for (int r = 0; r < 4; r++)
      red[kh][mh][kb * 4 + r][nt * 16 + ln] = acc[nt][r];
  __syncthreads();
  for (int i = t; i < 1024; i += 256) {
    int row = i >> 5, cp = i & 31;
    int mh2 = row >> 4, r2 = row & 15;
    int c0 = cp * 2;
    float v0 = red[0][mh2][r2][c0] + red[1][mh2][r2][c0] + bias[c0];
    float v1 = red[0][mh2][r2][c0 + 1] + red[1][mh2][r2][c0 + 1] + bias[c0 + 1];
    unsigned int pk = (unsigned)f2b(v0) | ((unsigned)f2b(v1) << 16);
    *(unsigned int*)(out + (size_t)(base + row) * PROJ + c0) = pk;
  }
}

// ---------------- k_attn: MFMA attention + fused mean-concat epilogue ----------------
__global__ __launch_bounds__(512) void k_attn(
    const float* __restrict__ x, const int* __restrict__ cidx,
    const int* __restrict__ eidx, const unsigned short* __restrict__ wcp,
    const unsigned short* __restrict__ wep, const int* __restrict__ c_off,
    const int* __restrict__ c_cnt, const int* __restrict__ c_list,
    const int* __restrict__ e_off, const int* __restrict__ e_cnt,
    const int* __restrict__ e_list, unsigned short* __restrict__ mcb) {
  __shared__ __align__(16) char smem[SMEM_BYTES];
  unsigned short* P_s  = (unsigned short*)(smem);
  unsigned short* we_s = (unsigned short*)(smem + REGB_OFF);
  unsigned short* wc_s = (unsigned short*)(smem + WC_S_OFF);
  unsigned short* evT  = (unsigned short*)(smem + REGB_OFF);
  unsigned int*   evT32 = (unsigned int*)(smem + REGB_OFF);
  float*          cn_s = (float*)(smem + REGB_OFF);
  float*          pp   = (float*)(smem);          // reuses dead P_s region post-PV
  int* ev_id = (int*)(smem + MISC_OFF);
  int* cl_id = (int*)(smem + MISC_OFF + 1024);

  int g = blockIdx.x >> 2;
  int ds = blockIdx.x & 3;
  int dsbase = ds * DW;
  int t = threadIdx.x, lane = t & 63, w = t >> 6;
  int ln = lane & 15, kb = lane >> 4;

  int ne = min(e_cnt[g], NE_CAP);
  int eoff = e_off[g];
  int ccnt_full = c_cnt[g];
  int nloc = min(ccnt_full, NCMAX);
  int coff = c_off[g];
  if (nloc <= 0) {
    int q = t >> 7, d = t & 127;
    mcb[(size_t)g * 4 * NHID + q * NHID + dsbase + d] = 0;
    return;
  }
  int KT = (ne + 31) >> 5;
  int NT = KT * 2;

  // ---- phase 0: stage ids + we_s + wc_s (raw bf16 copies) ----
  for (int e = t; e < NE_CAP; e += 512)
    ev_id[e] = (e < ne) ? (int)eidx[e_list[eoff + e]] : 0;
  if (t < NCMAX) cl_id[t] = (t < nloc) ? (int)cidx[c_list[coff + t]] : 0;
  {
    int q = t & 7, er = t >> 3;
    for (int base_ = 0; base_ < NE_CAP; base_ += 64) {
      int e = base_ + er;
      u16x8 v = (u16x8){0, 0, 0, 0, 0, 0, 0, 0};
      if (e < ne) v = *(const u16x8*)(wep + (size_t)e_list[eoff + e] * PROJ + q * 8);
      *(u16x8*)(we_s + e * WE_S_STRIDE + q * 8) = v;
    }
    for (int base_ = 0; base_ < NCMAX; base_ += 64) {
      int c = base_ + er;
      u16x8 v = (u16x8){0, 0, 0, 0, 0, 0, 0, 0};
      if (c < nloc) v = *(const u16x8*)(wcp + (size_t)c_list[coff + c] * PROJ + q * 8);
      *(u16x8*)(wc_s + c * WE_S_STRIDE + q * 8) = v;
    }
  }
  __syncthreads();

  // ---- score phase: S = wc @ we^T via MFMA ----
  {
    f32x4 sa[16];
#pragma unroll
    for (int i = 0; i < 16; i++) sa[i] = (f32x4){0.f, 0.f, 0.f, 0.f};
    const unsigned short* arow = wc_s + ((w << 4) + ln) * WE_S_STRIDE;
#pragma unroll
    for (int ks = 0; ks < 2; ks++) {
      s16x8 af = *(const s16x8*)(arow + ks * 32 + kb * 8);
#pragma unroll
      for (int nt = 0; nt < 16; nt++) {
        if (nt < NT) {
          s16x8 bf = *(const s16x8*)(we_s + (nt * 16 + ln) * WE_S_STRIDE + ks * 32 + kb * 8);
          sa[nt] = __builtin_amdgcn_mfma_f32_16x16x32_bf16(af, bf, sa[nt], 0, 0, 0);
        }
      }
    }
#pragma unroll
    for (int r = 0; r < 4; r++) {
      int claim = (w << 4) + (kb << 2) + r;
      float mx = -1e30f;
#pragma unroll
      for (int nt = 0; nt < 16; nt++) {
        if (nt < NT) {
          float v = sa[nt][r];
          v = (nt * 16 + ln < ne) ? v : -1e30f;
          sa[nt][r] = v;
          mx = fmaxf(mx, v);
        }
      }
      mx = fmaxf(mx, __shfl_xor(mx, 1));
      mx = fmaxf(mx, __shfl_xor(mx, 2));
      mx = fmaxf(mx, __shfl_xor(mx, 4));
      mx = fmaxf(mx, __shfl_xor(mx, 8));
      float sum = 0.f;
#pragma unroll
      for (int nt = 0; nt < 16; nt++) {
        if (nt < NT) {
          float p = __expf(sa[nt][r] - mx);
          sa[nt][r] = p;
          sum += p;
        }
      }
      sum += __shfl_xor(sum, 1);
      sum += __shfl_xor(sum, 2);
      sum += __shfl_xor(sum, 4);
      sum += __shfl_xor(sum, 8);
      float inv = 1.f / sum;
#pragma unroll
      for (int nt = 0; nt < 16; nt++) {
        if (nt < NT)
          P_s[claim * P_S_STRIDE + nt * 16 + ln] = f2b(sa[nt][r] * inv);
      }
    }
  }
  __syncthreads();

  // ---- stage evT[d][e] bf16 via float4 loads ----
#pragma unroll
  for (int it = 0; it < 8; it++) {
    int idx2 = it * 512 + t;
    int ep = idx2 & 127;
    int dq = idx2 >> 7;      // 0..31
    int d0 = dq * 4;
    int e0 = ep * 2;
    float4 va = make_float4(0.f, 0.f, 0.f, 0.f);
    float4 vb = make_float4(0.f, 0.f, 0.f, 0.f);
    if (e0 < ne)     va = *(const float4*)(x + (size_t)ev_id[e0] * NHID + dsbase + d0);
    if (e0 + 1 < ne) vb = *(const float4*)(x + (size_t)ev_id[e0 + 1] * NHID + dsbase + d0);
    evT32[(d0 + 0) * (P_S_STRIDE / 2) + ep] = (unsigned)f2b(va.x) | ((unsigned)f2b(vb.x) << 16);
    evT32[(d0 + 1) * (P_S_STRIDE / 2) + ep] = (unsigned)f2b(va.y) | ((unsigned)f2b(vb.y) << 16);
    evT32[(d0 + 2) * (P_S_STRIDE / 2) + ep] = (unsigned)f2b(va.z) | ((unsigned)f2b(vb.z) << 16);
    evT32[(d0 + 3) * (P_S_STRIDE / 2) + ep] = (unsigned)f2b(va.w) | ((unsigned)f2b(vb.w) << 16);
  }
  __syncthreads();

  // ---- PV phase ----
  int mw = w >> 1, nw = w & 1;
  int m0 = mw * 32, n0 = nw * 64;
  f32x4 pc[8];
#pragma unroll
  for (int i = 0; i < 8; i++) pc[i] = (f32x4){0.f, 0.f, 0.f, 0.f};
  {
    const unsigned short* prow0 = P_s + (m0 + ln) * P_S_STRIDE + kb * 8;
    const unsigned short* prow1 = prow0 + 16 * P_S_STRIDE;
#pragma unroll
    for (int kt = 0; kt < 8; kt++) {
      if (kt < KT) {
        int k0 = kt * 32;
        s16x8 a0 = *(const s16x8*)(prow0 + k0);
        s16x8 a1 = *(const s16x8*)(prow1 + k0);
#pragma unroll
        for (int nt = 0; nt < 4; nt++) {
          s16x8 bf = *(const s16x8*)(evT + (n0 + nt * 16 + ln) * P_S_STRIDE + k0 + kb * 8);
          pc[nt]     = __builtin_amdgcn_mfma_f32_16x16x32_bf16(a0, bf, pc[nt], 0, 0, 0);
          pc[4 + nt] = __builtin_amdgcn_mfma_f32_16x16x32_bf16(a1, bf, pc[4 + nt], 0, 0, 0);
        }
      }
    }
  }
  __syncthreads();   // P_s dead from here; pp may reuse its region

  // ---- dump cn to LDS ----
#pragma unroll
  for (int mi = 0; mi < 2; mi++) {
#pragma unroll
    for (int nt = 0; nt < 4; nt++) {
      f32x4 v = pc[mi * 4 + nt];
#pragma unroll
      for (int r = 0; r < 4; r++)
        cn_s[(m0 + mi * 16 + (kb << 2) + r) * CN_S_STRIDE + n0 + nt * 16 + ln] = v[r];
    }
  }
  __syncthreads();

  // ---- pooled sums: float4, 16 m-groups, partials into pp (P_s region) ----
  {
    int dq = (t & 31) * 4;
    int mg = t >> 5;     // 0..15
    float4 scl = make_float4(0.f, 0.f, 0.f, 0.f);
    float4 scn = make_float4(0.f, 0.f, 0.f, 0.f);
    float4 spr = make_float4(0.f, 0.f, 0.f, 0.f);
    for (int m = mg; m < nloc; m += 16) {
      float4 cl = *(const float4*)(x + (size_t)cl_id[m] * NHID + dsbase + dq);
      float4 cn = *(const float4*)(cn_s + m * CN_S_STRIDE + dq);
      scl.x += cl.x; scl.y += cl.y; scl.z += cl.z; scl.w += cl.w;
      scn.x += cn.x; scn.y += cn.y; scn.z += cn.z; scn.w += cn.w;
      spr.x += cl.x * cn.x; spr.y += cl.y * cn.y;
      spr.z += cl.z * cn.z; spr.w += cl.w * cn.w;
    }
    *(float4*)(pp + mg * 128 + dq) = scl;
    *(float4*)(pp + 2048 + mg * 128 + dq) = scn;
    *(float4*)(pp + 4096 + mg * 128 + dq) = spr;
  }
  __syncthreads();

  // ---- fused mean-concat epilogue ----
  {
    int q = t >> 7, d = t & 127;
    float inv = 1.f / (float)max(ccnt_full, 1);
    float v = 0.f;
    if (q == 0) {
#pragma unroll
      for (int mg = 0; mg < 16; mg++) v += pp[mg * 128 + d];
    } else if (q == 1) {
#pragma unroll
      for (int mg = 0; mg < 16; mg++) v += pp[2048 + mg * 128 + d];
    } else if (q == 2) {
#pragma unroll
      for (int mg = 0; mg < 16; mg++) v += pp[mg * 128 + d] - pp[2048 + mg * 128 + d];
    } else {
#pragma unroll
      for (int mg = 0; mg < 16; mg++) v += pp[4096 + mg * 128 + d];
    }
    mcb[(size_t)g * 4 * NHID + q * NHID + dsbase + d] = f2b(v * inv);
  }
}

// ---------------- k_out: 16 blocks, 32-col n-tiles, 2-way K-split ----------------
__global__ __launch_bounds__(512) void k_out(
    const unsigned short* __restrict__ mc, const unsigned short* __restrict__ WaT,
    const float* __restrict__ ba, float* __restrict__ out) {
  __shared__ float red[2][64][32];   // 16KB
  int n0 = blockIdx.x * 32;
  int t = threadIdx.x, lane = t & 63, wv = t >> 6;
  int mh = wv & 3, kh = wv >> 2;
  int ln = lane & 15, kb = lane >> 4;
  f32x4 acc[2];
  acc[0] = (f32x4){0.f, 0.f, 0.f, 0.f};
  acc[1] = (f32x4){0.f, 0.f, 0.f, 0.f};
  const unsigned short* arow = mc + (size_t)(mh * 16 + ln) * (4 * NHID) + kh * 1024;
  const unsigned short* wb = WaT + kh * 1024;
#pragma unroll 4
  for (int kt = 0; kt < 32; kt++) {
    int k0 = kt * 32 + kb * 8;
    s16x8 af = *(const s16x8*)(arow + k0);
#pragma unroll
    for (int nt = 0; nt < 2; nt++) {
      s16x8 bf = *(const s16x8*)(wb + (size_t)(n0 + nt * 16 + ln) * (4 * NHID) + k0);
      acc[nt] = __builtin_amdgcn_mfma_f32_16x16x32_bf16(af, bf, acc[nt], 0, 0, 0);
    }
  }
#pragma unroll
  for (int nt = 0; nt < 2; nt++)
#pragma unroll
    for (int r = 0; r < 4; r++)
      red[kh][mh * 16 + kb * 4 + r][nt * 16 + ln] = acc[nt][r];
  __syncthreads();
  for (int i = t; i < 2048; i += 512) {
    int row = i >> 5, col = i & 31;
    out[(size_t)row * NHID + n0 + col] = red[0][row][col] + red[1][row][col] + ba[n0 + col];
  }
}

extern "C" void kernel_launch(void* const* d_in, const int* in_sizes, int n_in,
                              void* d_out, int out_size, void* d_ws, size_t ws_size,
                              hipStream_t stream) {
  const float* x = (const float*)d_in[0];
  const int* batch = (const int*)d_in[1];
  const int* cidx = (const int*)d_in[2];
  const int* eidx = (const int*)d_in[3];
  const float* Wc = (const float*)d_in[4];
  const float* bc = (const float*)d_in[5];
  const float* We = (const float*)d_in[6];
  const float* be = (const float*)d_in[7];
  const float* Wa = (const float*)d_in[8];
  const float* ba = (const float*)d_in[9];
  float* out = (float*)d_out;

  char* w = (char*)d_ws;
  int* c_off = (int*)w;   w += NG * 4;
  int* c_cnt = (int*)w;   w += NG * 4;
  int* e_off = (int*)w;   w += NG * 4;
  int* e_cnt = (int*)w;   w += NG * 4;
  int* c_list = (int*)w;  w += NC * 4;
  int* e_list = (int*)w;  w += NEV * 4;
  unsigned short* wcp = (unsigned short*)w; w += (size_t)NC * PROJ * 2;
  unsigned short* wep = (unsigned short*)w; w += (size_t)NEV * PROJ * 2;
  unsigned short* WcT = (unsigned short*)w; w += (size_t)PROJ * NHID * 2;
  unsigned short* WeT = (unsigned short*)w; w += (size_t)PROJ * NHID * 2;
  unsigned short* WaT = (unsigned short*)w; w += (size_t)NHID * 4 * NHID * 2;
  unsigned short* mcb = (unsigned short*)w; w += (size_t)NG * 4 * NHID * 2;

  k_front<<<NG + 16 + 256, 256, 0, stream>>>(Wc, We, Wa, WcT, WeT, WaT, batch, cidx,
                                             eidx, c_off, c_cnt, c_list, e_off, e_cnt,
                                             e_list);
  k_proj<<<(NC + NEV) / 32, 256, 0, stream>>>(x, cidx, eidx, WcT, WeT, bc, be, wcp, wep);
  k_attn<<<NG * DSLICES, 512, 0, stream>>>(x, cidx, eidx, wcp, wep, c_off, c_cnt,
                                           c_list, e_off, e_cnt, e_list, mcb);
  k_out<<<16, 512, 0, stream>>>(mcb, WaT, ba, out);
}

// Round 7
// 72.040 us; speedup vs baseline: 1.6819x; 1.0101x over previous
//
#include <hip/hip_runtime.h>
#include <hip/hip_bf16.h>

#define NHID 512
#define PROJ 64
#define NC 4096
#define NEV 8192
#define NG 64
#define NCMAX 128
#define NE_CAP 256
#define DSLICES 4
#define DW 128

typedef __attribute__((ext_vector_type(8))) short s16x8;
typedef __attribute__((ext_vector_type(8))) unsigned short u16x8;
typedef __attribute__((ext_vector_type(4))) float f32x4;

// ---- k_attn LDS layout (bytes) ----
#define P_S_STRIDE 264            // bf16 elems per row (256 + 8 pad), 528B
#define P_S_BYTES  (NCMAX * P_S_STRIDE * 2)        // 67584
#define REGB_OFF   P_S_BYTES
#define WE_S_STRIDE 72            // bf16 elems (64 + 8 pad), 144B
#define WC_S_OFF   (REGB_OFF + NE_CAP * WE_S_STRIDE * 2)
#define CN_S_STRIDE 132           // f32 elems per row
#define MISC_OFF   (REGB_OFF + P_S_BYTES)
#define SMEM_BYTES (MISC_OFF + 1536)

static __device__ __forceinline__ unsigned short f2b(float f) {
  union { __hip_bfloat16 h; unsigned short u; } v;
  v.h = __float2bfloat16(f);
  return v.u;
}

// ---------------- compact_scan: stable compaction, 2 barriers total ----------------
template <int NPT>
__device__ __forceinline__ void compact_scan(
    const int* __restrict__ batch, const int* __restrict__ idx, int g,
    int* __restrict__ off_out, int* __restrict__ cnt_out, int* __restrict__ list,
    int* wtot, int* wless) {
  int t = threadIdx.x, lane = t & 63, w = t >> 6;
  int vals[NPT];
  int base_i = t * NPT;
  int eq = 0, less = 0;
#pragma unroll
  for (int j = 0; j < NPT; j++) {
    int v = batch[idx[base_i + j]];
    vals[j] = v;
    eq += (v == g) ? 1 : 0;
    less += (v < g) ? 1 : 0;
  }
  int s = eq;
#pragma unroll
  for (int off = 1; off < 64; off <<= 1) {
    int o = __shfl_up(s, off);
    if (lane >= off) s += o;
  }
  int ls = less;
#pragma unroll
  for (int off = 32; off; off >>= 1) ls += __shfl_xor(ls, off);
  if (lane == 63) wtot[w] = s;
  if (lane == 0) wless[w] = ls;
  __syncthreads();
  int wbase = 0;
#pragma unroll
  for (int k = 0; k < 4; k++)
    if (k < w) wbase += wtot[k];
  int base = wless[0] + wless[1] + wless[2] + wless[3];
  int pos = base + wbase + (s - eq);
#pragma unroll
  for (int j = 0; j < NPT; j++) {
    if (vals[j] == g) list[pos++] = base_i + j;
  }
  if (t == 255) {
    cnt_out[g] = wbase + s;
    off_out[g] = base;
  }
  __syncthreads();
}

// ---------------- k_front: compaction (blocks 0..63) + weight transposes ----------------
__global__ __launch_bounds__(256) void k_front(
    const float* __restrict__ Wc, const float* __restrict__ We,
    const float* __restrict__ Wa, unsigned short* __restrict__ WcT,
    unsigned short* __restrict__ WeT, unsigned short* __restrict__ WaT,
    const int* __restrict__ batch, const int* __restrict__ cidx,
    const int* __restrict__ eidx, int* __restrict__ c_off, int* __restrict__ c_cnt,
    int* __restrict__ c_list, int* __restrict__ e_off, int* __restrict__ e_cnt,
    int* __restrict__ e_list) {
  __shared__ __align__(16) char sm[64 * 65 * 4];
  int b = blockIdx.x;
  if (b < NG) {
    int* wtot = (int*)sm;
    int* wless = ((int*)sm) + 4;
    compact_scan<NC / 256>(batch, cidx, b, c_off, c_cnt, c_list, wtot, wless);
    compact_scan<NEV / 256>(batch, eidx, b, e_off, e_cnt, e_list, wtot, wless);
    return;
  }
  int tb = b - NG;
  float(*ts)[65] = (float(*)[65])sm;
  const float* src; unsigned short* dst; int K, N, kt, nt;
  if (tb < 8)       { src = Wc; dst = WcT; K = 512;  N = 64;  kt = tb;           nt = 0; }
  else if (tb < 16) { src = We; dst = WeT; K = 512;  N = 64;  kt = tb - 8;       nt = 0; }
  else              { src = Wa; dst = WaT; K = 2048; N = 512; kt = (tb - 16) >> 3; nt = (tb - 16) & 7; }
  int k0 = kt * 64, n0 = nt * 64;
  int t = threadIdx.x;
  int c = t & 63, r0 = t >> 6;
#pragma unroll
  for (int p = 0; p < 16; p++) {
    int r = r0 * 16 + p;
    ts[r][c] = src[(size_t)(k0 + r) * N + n0 + c];
  }
  __syncthreads();
  int n = t >> 2, q = t & 3;
  unsigned short tmp[16];
#pragma unroll
  for (int j = 0; j < 16; j++) tmp[j] = f2b(ts[q * 16 + j][n]);
  u16x8* dp = (u16x8*)(dst + (size_t)(n0 + n) * K + k0 + q * 16);
  dp[0] = *(u16x8*)tmp;
  dp[1] = *(u16x8*)(tmp + 8);
}

// ---------------- k_proj: MFMA GEMM, 2-way K-split, 4 waves/block ----------------
__global__ __launch_bounds__(256) void k_proj(
    const float* __restrict__ x, const int* __restrict__ cidx,
    const int* __restrict__ eidx, const unsigned short* __restrict__ WcT,
    const unsigned short* __restrict__ WeT, const float* __restrict__ bc,
    const float* __restrict__ be, unsigned short* __restrict__ wcp,
    unsigned short* __restrict__ wep) {
  __shared__ float red[2][2][16][64];   // [kh][mh][row][col] = 16KB
  int b = blockIdx.x;
  const int* idx; const unsigned short* WT; const float* bias;
  unsigned short* out; int base;
  if (b < NC / 32) { idx = cidx; WT = WcT; bias = bc; out = wcp; base = b * 32; }
  else             { idx = eidx; WT = WeT; bias = be; out = wep; base = (b - NC / 32) * 32; }
  int t = threadIdx.x, lane = t & 63, w = t >> 6;
  int mh = w & 1, kh = w >> 1;
  int ln = lane & 15, kb = lane >> 4;
  const float* xr = x + (size_t)idx[base + mh * 16 + ln] * NHID + kh * 256;
  const unsigned short* wb = WT + kh * 256;
  f32x4 acc[4];
#pragma unroll
  for (int nt = 0; nt < 4; nt++) acc[nt] = (f32x4){0.f, 0.f, 0.f, 0.f};
#pragma unroll
  for (int kt = 0; kt < 8; kt++) {
    int k0 = kt * 32 + kb * 8;
    float4 p0 = *(const float4*)(xr + k0);
    float4 p1 = *(const float4*)(xr + k0 + 4);
    s16x8 a;
    a[0] = (short)f2b(p0.x); a[1] = (short)f2b(p0.y);
    a[2] = (short)f2b(p0.z); a[3] = (short)f2b(p0.w);
    a[4] = (short)f2b(p1.x); a[5] = (short)f2b(p1.y);
    a[6] = (short)f2b(p1.z); a[7] = (short)f2b(p1.w);
#pragma unroll
    for (int nt = 0; nt < 4; nt++) {
      s16x8 bf = *(const s16x8*)(wb + (size_t)(nt * 16 + ln) * NHID + k0);
      acc[nt] = __builtin_amdgcn_mfma_f32_16x16x32_bf16(a, bf, acc[nt], 0, 0, 0);
    }
  }
#pragma unroll
  for (int nt = 0; nt < 4; nt++)
#pragma unroll
    for (int r = 0; r < 4; r++)
      red[kh][mh][kb * 4 + r][nt * 16 + ln] = acc[nt][r];
  __syncthreads();
  for (int i = t; i < 1024; i += 256) {
    int row = i >> 5, cp = i & 31;
    int mh2 = row >> 4, r2 = row & 15;
    int c0 = cp * 2;
    float v0 = red[0][mh2][r2][c0] + red[1][mh2][r2][c0] + bias[c0];
    float v1 = red[0][mh2][r2][c0 + 1] + red[1][mh2][r2][c0 + 1] + bias[c0 + 1];
    unsigned int pk = (unsigned)f2b(v0) | ((unsigned)f2b(v1) << 16);
    *(unsigned int*)(out + (size_t)(base + row) * PROJ + c0) = pk;
  }
}

// ---------------- k_attn: MFMA attention, T14 async-staged loads ----------------
__global__ __launch_bounds__(512, 2) void k_attn(
    const float* __restrict__ x, const int* __restrict__ cidx,
    const int* __restrict__ eidx, const unsigned short* __restrict__ wcp,
    const unsigned short* __restrict__ wep, const int* __restrict__ c_off,
    const int* __restrict__ c_cnt, const int* __restrict__ c_list,
    const int* __restrict__ e_off, const int* __restrict__ e_cnt,
    const int* __restrict__ e_list, unsigned short* __restrict__ mcb) {
  __shared__ __align__(16) char smem[SMEM_BYTES];
  unsigned short* P_s  = (unsigned short*)(smem);
  unsigned short* we_s = (unsigned short*)(smem + REGB_OFF);
  unsigned short* wc_s = (unsigned short*)(smem + WC_S_OFF);
  unsigned short* evT  = (unsigned short*)(smem + REGB_OFF);
  unsigned int*   evT32 = (unsigned int*)(smem + REGB_OFF);
  float*          cn_s = (float*)(smem + REGB_OFF);
  float*          pp   = (float*)(smem);          // reuses dead P_s region post-PV
  int* ev_id = (int*)(smem + MISC_OFF);
  int* cl_id = (int*)(smem + MISC_OFF + 1024);

  int g = blockIdx.x >> 2;
  int ds = blockIdx.x & 3;
  int dsbase = ds * DW;
  int t = threadIdx.x, lane = t & 63, w = t >> 6;
  int ln = lane & 15, kb = lane >> 4;

  int ne = min(e_cnt[g], NE_CAP);
  int eoff = e_off[g];
  int ccnt_full = c_cnt[g];
  int nloc = min(ccnt_full, NCMAX);
  int coff = c_off[g];
  if (nloc <= 0) {
    int q = t >> 7, d = t & 127;
    mcb[(size_t)g * 4 * NHID + q * NHID + dsbase + d] = 0;
    return;
  }
  int KT = (ne + 31) >> 5;
  int NT = KT * 2;

  // ---- phase 0: stage ids + we_s + wc_s (raw bf16 copies) ----
  for (int e = t; e < NE_CAP; e += 512)
    ev_id[e] = (e < ne) ? (int)eidx[e_list[eoff + e]] : 0;
  if (t < NCMAX) cl_id[t] = (t < nloc) ? (int)cidx[c_list[coff + t]] : 0;
  {
    int q = t & 7, er = t >> 3;
    for (int base_ = 0; base_ < NE_CAP; base_ += 64) {
      int e = base_ + er;
      u16x8 v = (u16x8){0, 0, 0, 0, 0, 0, 0, 0};
      if (e < ne) v = *(const u16x8*)(wep + (size_t)e_list[eoff + e] * PROJ + q * 8);
      *(u16x8*)(we_s + e * WE_S_STRIDE + q * 8) = v;
    }
    for (int base_ = 0; base_ < NCMAX; base_ += 64) {
      int c = base_ + er;
      u16x8 v = (u16x8){0, 0, 0, 0, 0, 0, 0, 0};
      if (c < nloc) v = *(const u16x8*)(wcp + (size_t)c_list[coff + c] * PROJ + q * 8);
      *(u16x8*)(wc_s + c * WE_S_STRIDE + q * 8) = v;
    }
  }
  __syncthreads();

  // ---- T14: issue evT global loads into registers NOW; score hides latency ----
  float4 eva[8], evb[8];
#pragma unroll
  for (int it = 0; it < 8; it++) {
    int idx2 = it * 512 + t;
    int ep = idx2 & 127;
    int dq = idx2 >> 7;      // 0..31
    int d0 = dq * 4;
    int e0 = ep * 2;
    eva[it] = make_float4(0.f, 0.f, 0.f, 0.f);
    evb[it] = make_float4(0.f, 0.f, 0.f, 0.f);
    if (e0 < ne)     eva[it] = *(const float4*)(x + (size_t)ev_id[e0] * NHID + dsbase + d0);
    if (e0 + 1 < ne) evb[it] = *(const float4*)(x + (size_t)ev_id[e0 + 1] * NHID + dsbase + d0);
  }

  // ---- score phase: S = wc @ we^T via MFMA ----
  {
    f32x4 sa[16];
#pragma unroll
    for (int i = 0; i < 16; i++) sa[i] = (f32x4){0.f, 0.f, 0.f, 0.f};
    const unsigned short* arow = wc_s + ((w << 4) + ln) * WE_S_STRIDE;
#pragma unroll
    for (int ks = 0; ks < 2; ks++) {
      s16x8 af = *(const s16x8*)(arow + ks * 32 + kb * 8);
#pragma unroll
      for (int nt = 0; nt < 16; nt++) {
        if (nt < NT) {
          s16x8 bf = *(const s16x8*)(we_s + (nt * 16 + ln) * WE_S_STRIDE + ks * 32 + kb * 8);
          sa[nt] = __builtin_amdgcn_mfma_f32_16x16x32_bf16(af, bf, sa[nt], 0, 0, 0);
        }
      }
    }
#pragma unroll
    for (int r = 0; r < 4; r++) {
      int claim = (w << 4) + (kb << 2) + r;
      float mx = -1e30f;
#pragma unroll
      for (int nt = 0; nt < 16; nt++) {
        if (nt < NT) {
          float v = sa[nt][r];
          v = (nt * 16 + ln < ne) ? v : -1e30f;
          sa[nt][r] = v;
          mx = fmaxf(mx, v);
        }
      }
      mx = fmaxf(mx, __shfl_xor(mx, 1));
      mx = fmaxf(mx, __shfl_xor(mx, 2));
      mx = fmaxf(mx, __shfl_xor(mx, 4));
      mx = fmaxf(mx, __shfl_xor(mx, 8));
      float sum = 0.f;
#pragma unroll
      for (int nt = 0; nt < 16; nt++) {
        if (nt < NT) {
          float p = __expf(sa[nt][r] - mx);
          sa[nt][r] = p;
          sum += p;
        }
      }
      sum += __shfl_xor(sum, 1);
      sum += __shfl_xor(sum, 2);
      sum += __shfl_xor(sum, 4);
      sum += __shfl_xor(sum, 8);
      float inv = 1.f / sum;
#pragma unroll
      for (int nt = 0; nt < 16; nt++) {
        if (nt < NT)
          P_s[claim * P_S_STRIDE + nt * 16 + ln] = f2b(sa[nt][r] * inv);
      }
    }
  }
  __syncthreads();   // we_s dead; P_s ready; evT loads drained here

  // ---- write evT[d][e] bf16 from staged registers ----
#pragma unroll
  for (int it = 0; it < 8; it++) {
    int idx2 = it * 512 + t;
    int ep = idx2 & 127;
    int dq = idx2 >> 7;
    int d0 = dq * 4;
    float4 va = eva[it], vb = evb[it];
    evT32[(d0 + 0) * (P_S_STRIDE / 2) + ep] = (unsigned)f2b(va.x) | ((unsigned)f2b(vb.x) << 16);
    evT32[(d0 + 1) * (P_S_STRIDE / 2) + ep] = (unsigned)f2b(va.y) | ((unsigned)f2b(vb.y) << 16);
    evT32[(d0 + 2) * (P_S_STRIDE / 2) + ep] = (unsigned)f2b(va.z) | ((unsigned)f2b(vb.z) << 16);
    evT32[(d0 + 3) * (P_S_STRIDE / 2) + ep] = (unsigned)f2b(va.w) | ((unsigned)f2b(vb.w) << 16);
  }
  __syncthreads();

  // ---- T14: issue claim-row loads for pooled phase; PV hides latency ----
  int dq4 = (t & 31) * 4;
  int mg = t >> 5;     // 0..15
  float4 cl_r[8];
#pragma unroll
  for (int mi = 0; mi < 8; mi++) {
    int m = mg + mi * 16;
    cl_r[mi] = make_float4(0.f, 0.f, 0.f, 0.f);
    if (m < nloc)
      cl_r[mi] = *(const float4*)(x + (size_t)cl_id[m] * NHID + dsbase + dq4);
  }

  // ---- PV phase ----
  int mw = w >> 1, nw = w & 1;
  int m0 = mw * 32, n0 = nw * 64;
  f32x4 pc[8];
#pragma unroll
  for (int i = 0; i < 8; i++) pc[i] = (f32x4){0.f, 0.f, 0.f, 0.f};
  {
    const unsigned short* prow0 = P_s + (m0 + ln) * P_S_STRIDE + kb * 8;
    const unsigned short* prow1 = prow0 + 16 * P_S_STRIDE;
#pragma unroll
    for (int kt = 0; kt < 8; kt++) {
      if (kt < KT) {
        int k0 = kt * 32;
        s16x8 a0 = *(const s16x8*)(prow0 + k0);
        s16x8 a1 = *(const s16x8*)(prow1 + k0);
#pragma unroll
        for (int nt = 0; nt < 4; nt++) {
          s16x8 bf = *(const s16x8*)(evT + (n0 + nt * 16 + ln) * P_S_STRIDE + k0 + kb * 8);
          pc[nt]     = __builtin_amdgcn_mfma_f32_16x16x32_bf16(a0, bf, pc[nt], 0, 0, 0);
          pc[4 + nt] = __builtin_amdgcn_mfma_f32_16x16x32_bf16(a1, bf, pc[4 + nt], 0, 0, 0);
        }
      }
    }
  }
  __syncthreads();   // P_s dead from here; pp may reuse its region

  // ---- dump cn to LDS ----
#pragma unroll
  for (int mi = 0; mi < 2; mi++) {
#pragma unroll
    for (int nt = 0; nt < 4; nt++) {
      f32x4 v = pc[mi * 4 + nt];
#pragma unroll
      for (int r = 0; r < 4; r++)
        cn_s[(m0 + mi * 16 + (kb << 2) + r) * CN_S_STRIDE + n0 + nt * 16 + ln] = v[r];
    }
  }
  __syncthreads();

  // ---- pooled sums: staged claim regs + cn_s, partials into pp ----
  {
    float4 scl = make_float4(0.f, 0.f, 0.f, 0.f);
    float4 scn = make_float4(0.f, 0.f, 0.f, 0.f);
    float4 spr = make_float4(0.f, 0.f, 0.f, 0.f);
#pragma unroll
    for (int mi = 0; mi < 8; mi++) {
      int m = mg + mi * 16;
      if (m < nloc) {
        float4 cl = cl_r[mi];
        float4 cn = *(const float4*)(cn_s + m * CN_S_STRIDE + dq4);
        scl.x += cl.x; scl.y += cl.y; scl.z += cl.z; scl.w += cl.w;
        scn.x += cn.x; scn.y += cn.y; scn.z += cn.z; scn.w += cn.w;
        spr.x += cl.x * cn.x; spr.y += cl.y * cn.y;
        spr.z += cl.z * cn.z; spr.w += cl.w * cn.w;
      }
    }
    *(float4*)(pp + mg * 128 + dq4) = scl;
    *(float4*)(pp + 2048 + mg * 128 + dq4) = scn;
    *(float4*)(pp + 4096 + mg * 128 + dq4) = spr;
  }
  __syncthreads();

  // ---- fused mean-concat epilogue ----
  {
    int q = t >> 7, d = t & 127;
    float inv = 1.f / (float)max(ccnt_full, 1);
    float v = 0.f;
    if (q == 0) {
#pragma unroll
      for (int mg2 = 0; mg2 < 16; mg2++) v += pp[mg2 * 128 + d];
    } else if (q == 1) {
#pragma unroll
      for (int mg2 = 0; mg2 < 16; mg2++) v += pp[2048 + mg2 * 128 + d];
    } else if (q == 2) {
#pragma unroll
      for (int mg2 = 0; mg2 < 16; mg2++) v += pp[mg2 * 128 + d] - pp[2048 + mg2 * 128 + d];
    } else {
#pragma unroll
      for (int mg2 = 0; mg2 < 16; mg2++) v += pp[4096 + mg2 * 128 + d];
    }
    mcb[(size_t)g * 4 * NHID + q * NHID + dsbase + d] = f2b(v * inv);
  }
}

// ---------------- k_out: 16 blocks, 32-col n-tiles, 2-way K-split ----------------
__global__ __launch_bounds__(512) void k_out(
    const unsigned short* __restrict__ mc, const unsigned short* __restrict__ WaT,
    const float* __restrict__ ba, float* __restrict__ out) {
  __shared__ float red[2][64][32];   // 16KB
  int n0 = blockIdx.x * 32;
  int t = threadIdx.x, lane = t & 63, wv = t >> 6;
  int mh = wv & 3, kh = wv >> 2;
  int ln = lane & 15, kb = lane >> 4;
  f32x4 acc[2];
  acc[0] = (f32x4){0.f, 0.f, 0.f, 0.f};
  acc[1] = (f32x4){0.f, 0.f, 0.f, 0.f};
  const unsigned short* arow = mc + (size_t)(mh * 16 + ln) * (4 * NHID) + kh * 1024;
  const unsigned short* wb = WaT + kh * 1024;
#pragma unroll 4
  for (int kt = 0; kt < 32; kt++) {
    int k0 = kt * 32 + kb * 8;
    s16x8 af = *(const s16x8*)(arow + k0);
#pragma unroll
    for (int nt = 0; nt < 2; nt++) {
      s16x8 bf = *(const s16x8*)(wb + (size_t)(n0 + nt * 16 + ln) * (4 * NHID) + k0);
      acc[nt] = __builtin_amdgcn_mfma_f32_16x16x32_bf16(af, bf, acc[nt], 0, 0, 0);
    }
  }
#pragma unroll
  for (int nt = 0; nt < 2; nt++)
#pragma unroll
    for (int r = 0; r < 4; r++)
      red[kh][mh * 16 + kb * 4 + r][nt * 16 + ln] = acc[nt][r];
  __syncthreads();
  for (int i = t; i < 2048; i += 512) {
    int row = i >> 5, col = i & 31;
    out[(size_t)row * NHID + n0 + col] = red[0][row][col] + red[1][row][col] + ba[n0 + col];
  }
}

extern "C" void kernel_launch(void* const* d_in, const int* in_sizes, int n_in,
                              void* d_out, int out_size, void* d_ws, size_t ws_size,
                              hipStream_t stream) {
  const float* x = (const float*)d_in[0];
  const int* batch = (const int*)d_in[1];
  const int* cidx = (const int*)d_in[2];
  const int* eidx = (const int*)d_in[3];
  const float* Wc = (const float*)d_in[4];
  const float* bc = (const float*)d_in[5];
  const float* We = (const float*)d_in[6];
  const float* be = (const float*)d_in[7];
  const float* Wa = (const float*)d_in[8];
  const float* ba = (const float*)d_in[9];
  float* out = (float*)d_out;

  char* w = (char*)d_ws;
  int* c_off = (int*)w;   w += NG * 4;
  int* c_cnt = (int*)w;   w += NG * 4;
  int* e_off = (int*)w;   w += NG * 4;
  int* e_cnt = (int*)w;   w += NG * 4;
  int* c_list = (int*)w;  w += NC * 4;
  int* e_list = (int*)w;  w += NEV * 4;
  unsigned short* wcp = (unsigned short*)w; w += (size_t)NC * PROJ * 2;
  unsigned short* wep = (unsigned short*)w; w += (size_t)NEV * PROJ * 2;
  unsigned short* WcT = (unsigned short*)w; w += (size_t)PROJ * NHID * 2;
  unsigned short* WeT = (unsigned short*)w; w += (size_t)PROJ * NHID * 2;
  unsigned short* WaT = (unsigned short*)w; w += (size_t)NHID * 4 * NHID * 2;
  unsigned short* mcb = (unsigned short*)w; w += (size_t)NG * 4 * NHID * 2;

  k_front<<<NG + 16 + 256, 256, 0, stream>>>(Wc, We, Wa, WcT, WeT, WaT, batch, cidx,
                                             eidx, c_off, c_cnt, c_list, e_off, e_cnt,
                                             e_list);
  k_proj<<<(NC + NEV) / 32, 256, 0, stream>>>(x, cidx, eidx, WcT, WeT, bc, be, wcp, wep);
  k_attn<<<NG * DSLICES, 512, 0, stream>>>(x, cidx, eidx, wcp, wep, c_off, c_cnt,
                                           c_list, e_off, e_cnt, e_list, mcb);
  k_out<<<16, 512, 0, stream>>>(mcb, WaT, ba, out);
}

// Round 8
// 58.298 us; speedup vs baseline: 2.0783x; 1.2357x over previous
//
#include <hip/hip_runtime.h>
#include <hip/hip_bf16.h>

#define NHID 512
#define PROJ 64
#define NC 4096
#define NEV 8192
#define NG 64
#define NCMAX 128
#define NE_CAP 256
#define DSLICES 4
#define DW 128

typedef __attribute__((ext_vector_type(8))) short s16x8;
typedef __attribute__((ext_vector_type(8))) unsigned short u16x8;
typedef __attribute__((ext_vector_type(4))) float f32x4;

// ---- k_attn LDS layout (bytes) ----
#define P_S_STRIDE 264            // bf16 elems per row (256 + 8 pad), 528B
#define P_S_BYTES  (NCMAX * P_S_STRIDE * 2)        // 67584
#define REGB_OFF   P_S_BYTES
#define WE_S_STRIDE 72            // bf16 elems (64 + 8 pad), 144B
#define WC_S_OFF   (REGB_OFF + NE_CAP * WE_S_STRIDE * 2)
#define CN_S_STRIDE 132           // f32 elems per row
#define MISC_OFF   (REGB_OFF + P_S_BYTES)
#define SMEM_BYTES (MISC_OFF + 1536)

static __device__ __forceinline__ unsigned short f2b(float f) {
  union { __hip_bfloat16 h; unsigned short u; } v;
  v.h = __float2bfloat16(f);
  return v.u;
}

// ---------------- compact_pairs: stable compaction -> (orig_pos, node_id) ----------------
template <int NPT>
__device__ __forceinline__ void compact_pairs(
    const int* __restrict__ batch, const int* __restrict__ idx, int g,
    int* __restrict__ off_out, int* __restrict__ cnt_out, int2* __restrict__ pairs) {
  __shared__ int wtot[4], wless[4];
  int t = threadIdx.x, lane = t & 63, w = t >> 6;
  int vals[NPT], nid[NPT];
  int base_i = t * NPT;
  int eq = 0, less = 0;
#pragma unroll
  for (int j = 0; j < NPT; j++) {
    int node = idx[base_i + j];
    int v = batch[node];
    vals[j] = v;
    nid[j] = node;
    eq += (v == g) ? 1 : 0;
    less += (v < g) ? 1 : 0;
  }
  int s = eq;
#pragma unroll
  for (int off = 1; off < 64; off <<= 1) {
    int o = __shfl_up(s, off);
    if (lane >= off) s += o;
  }
  int ls = less;
#pragma unroll
  for (int off = 32; off; off >>= 1) ls += __shfl_xor(ls, off);
  if (lane == 63) wtot[w] = s;
  if (lane == 0) wless[w] = ls;
  __syncthreads();
  int wbase = 0;
#pragma unroll
  for (int k = 0; k < 4; k++)
    if (k < w) wbase += wtot[k];
  int base = wless[0] + wless[1] + wless[2] + wless[3];
  int pos = base + wbase + (s - eq);
#pragma unroll
  for (int j = 0; j < NPT; j++) {
    if (vals[j] == g) pairs[pos++] = make_int2(base_i + j, nid[j]);
  }
  if (t == 255) {
    cnt_out[g] = wbase + s;
    off_out[g] = base;
  }
}

// ---------------- k_front: Wc/We transposes (0..15) + claim comp (16..79) + evid comp (80..143) ----------------
__global__ __launch_bounds__(256) void k_front(
    const float* __restrict__ Wc, const float* __restrict__ We,
    unsigned short* __restrict__ WcT, unsigned short* __restrict__ WeT,
    const int* __restrict__ batch, const int* __restrict__ cidx,
    const int* __restrict__ eidx, int* __restrict__ c_off, int* __restrict__ c_cnt,
    int2* __restrict__ c_pair, int* __restrict__ e_off, int* __restrict__ e_cnt,
    int2* __restrict__ e_pair) {
  int b = blockIdx.x;
  if (b < 16) {
    __shared__ float ts[64][65];
    const float* src = (b < 8) ? Wc : We;
    unsigned short* dst = (b < 8) ? WcT : WeT;
    int k0 = (b & 7) * 64;
    int t = threadIdx.x;
    int c = t & 63, r0 = t >> 6;
#pragma unroll
    for (int p = 0; p < 16; p++) {
      int r = r0 * 16 + p;
      ts[r][c] = src[(size_t)(k0 + r) * 64 + c];
    }
    __syncthreads();
    int n = t >> 2, q = t & 3;
    unsigned short tmp[16];
#pragma unroll
    for (int j = 0; j < 16; j++) tmp[j] = f2b(ts[q * 16 + j][n]);
    u16x8* dp = (u16x8*)(dst + (size_t)n * NHID + k0 + q * 16);
    dp[0] = *(u16x8*)tmp;
    dp[1] = *(u16x8*)(tmp + 8);
  } else if (b < 80) {
    compact_pairs<NC / 256>(batch, cidx, b - 16, c_off, c_cnt, c_pair);
  } else {
    compact_pairs<NEV / 256>(batch, eidx, b - 80, e_off, e_cnt, e_pair);
  }
}

// ---------------- k_proj: 768 GEMM blocks (16 rows, 4-way K-split) + 256 Wa-transpose blocks ----------------
__global__ __launch_bounds__(256) void k_proj(
    const float* __restrict__ x, const int* __restrict__ cidx,
    const int* __restrict__ eidx, const unsigned short* __restrict__ WcT,
    const unsigned short* __restrict__ WeT, const float* __restrict__ bc,
    const float* __restrict__ be, const float* __restrict__ Wa,
    unsigned short* __restrict__ WaT, unsigned short* __restrict__ wcp,
    unsigned short* __restrict__ wep) {
  __shared__ __align__(16) char sm[64 * 65 * 4];
  int b = blockIdx.x;
  int t = threadIdx.x;
  if (b >= 768) {
    // Wa [2048][512] f32 -> WaT [512][2048] bf16, 64x64 tiles
    int tb = b - 768;
    float(*ts)[65] = (float(*)[65])sm;
    int k0 = (tb >> 3) * 64, n0 = (tb & 7) * 64;
    int c = t & 63, r0 = t >> 6;
#pragma unroll
    for (int p = 0; p < 16; p++) {
      int r = r0 * 16 + p;
      ts[r][c] = Wa[(size_t)(k0 + r) * NHID + n0 + c];
    }
    __syncthreads();
    int n = t >> 2, q = t & 3;
    unsigned short tmp[16];
#pragma unroll
    for (int j = 0; j < 16; j++) tmp[j] = f2b(ts[q * 16 + j][n]);
    u16x8* dp = (u16x8*)(WaT + (size_t)(n0 + n) * (4 * NHID) + k0 + q * 16);
    dp[0] = *(u16x8*)tmp;
    dp[1] = *(u16x8*)(tmp + 8);
    return;
  }
  float(*red)[16][64] = (float(*)[16][64])sm;   // [4][16][64] = 16KB
  const int* idx; const unsigned short* WT; const float* bias;
  unsigned short* out; int base;
  if (b < NC / 16) { idx = cidx; WT = WcT; bias = bc; out = wcp; base = b * 16; }
  else             { idx = eidx; WT = WeT; bias = be; out = wep; base = (b - NC / 16) * 16; }
  int lane = t & 63, kh = t >> 6;     // kh = 4-way K-split
  int ln = lane & 15, kb = lane >> 4;
  const float* xr = x + (size_t)idx[base + ln] * NHID + kh * 128;
  const unsigned short* wb = WT + kh * 128;
  f32x4 acc[4];
#pragma unroll
  for (int nt = 0; nt < 4; nt++) acc[nt] = (f32x4){0.f, 0.f, 0.f, 0.f};
#pragma unroll
  for (int kt = 0; kt < 4; kt++) {
    int k0 = kt * 32 + kb * 8;
    float4 p0 = *(const float4*)(xr + k0);
    float4 p1 = *(const float4*)(xr + k0 + 4);
    s16x8 a;
    a[0] = (short)f2b(p0.x); a[1] = (short)f2b(p0.y);
    a[2] = (short)f2b(p0.z); a[3] = (short)f2b(p0.w);
    a[4] = (short)f2b(p1.x); a[5] = (short)f2b(p1.y);
    a[6] = (short)f2b(p1.z); a[7] = (short)f2b(p1.w);
#pragma unroll
    for (int nt = 0; nt < 4; nt++) {
      s16x8 bf = *(const s16x8*)(wb + (size_t)(nt * 16 + ln) * NHID + k0);
      acc[nt] = __builtin_amdgcn_mfma_f32_16x16x32_bf16(a, bf, acc[nt], 0, 0, 0);
    }
  }
#pragma unroll
  for (int nt = 0; nt < 4; nt++)
#pragma unroll
    for (int r = 0; r < 4; r++)
      red[kh][kb * 4 + r][nt * 16 + ln] = acc[nt][r];
  __syncthreads();
  for (int i = t; i < 512; i += 256) {
    int row = i >> 5, cp = i & 31;
    int c0 = cp * 2;
    float v0 = red[0][row][c0] + red[1][row][c0] + red[2][row][c0] + red[3][row][c0] + bias[c0];
    float v1 = red[0][row][c0 + 1] + red[1][row][c0 + 1] + red[2][row][c0 + 1] + red[3][row][c0 + 1] + bias[c0 + 1];
    unsigned int pk = (unsigned)f2b(v0) | ((unsigned)f2b(v1) << 16);
    *(unsigned int*)(out + (size_t)(base + row) * PROJ + c0) = pk;
  }
}

// ---------------- k_attn: MFMA attention, pair-based 1-level gathers, T14 staging ----------------
__global__ __launch_bounds__(512, 2) void k_attn(
    const float* __restrict__ x, const unsigned short* __restrict__ wcp,
    const unsigned short* __restrict__ wep, const int* __restrict__ c_off,
    const int* __restrict__ c_cnt, const int2* __restrict__ c_pair,
    const int* __restrict__ e_off, const int* __restrict__ e_cnt,
    const int2* __restrict__ e_pair, unsigned short* __restrict__ mcb) {
  __shared__ __align__(16) char smem[SMEM_BYTES];
  unsigned short* P_s  = (unsigned short*)(smem);
  unsigned short* we_s = (unsigned short*)(smem + REGB_OFF);
  unsigned short* wc_s = (unsigned short*)(smem + WC_S_OFF);
  unsigned short* evT  = (unsigned short*)(smem + REGB_OFF);
  unsigned int*   evT32 = (unsigned int*)(smem + REGB_OFF);
  float*          cn_s = (float*)(smem + REGB_OFF);
  float*          pp   = (float*)(smem);          // reuses dead P_s region post-PV
  int* ev_id = (int*)(smem + MISC_OFF);
  int* cl_id = (int*)(smem + MISC_OFF + 1024);

  int g = blockIdx.x >> 2;
  int ds = blockIdx.x & 3;
  int dsbase = ds * DW;
  int t = threadIdx.x, lane = t & 63, w = t >> 6;
  int ln = lane & 15, kb = lane >> 4;

  int ne = min(e_cnt[g], NE_CAP);
  int eoff = e_off[g];
  int ccnt_full = c_cnt[g];
  int nloc = min(ccnt_full, NCMAX);
  int coff = c_off[g];
  if (nloc <= 0) {
    int q = t >> 7, d = t & 127;
    mcb[(size_t)g * 4 * NHID + q * NHID + dsbase + d] = 0;
    return;
  }
  int KT = (ne + 31) >> 5;
  int NT = KT * 2;

  // ---- phase 0: stage ids + we_s + wc_s (1-level gathers via pairs) ----
  for (int e = t; e < NE_CAP; e += 512)
    ev_id[e] = (e < ne) ? e_pair[eoff + e].y : 0;
  if (t < NCMAX) cl_id[t] = (t < nloc) ? c_pair[coff + t].y : 0;
  {
    int q = t & 7, er = t >> 3;
    for (int base_ = 0; base_ < NE_CAP; base_ += 64) {
      int e = base_ + er;
      u16x8 v = (u16x8){0, 0, 0, 0, 0, 0, 0, 0};
      if (e < ne) v = *(const u16x8*)(wep + (size_t)e_pair[eoff + e].x * PROJ + q * 8);
      *(u16x8*)(we_s + e * WE_S_STRIDE + q * 8) = v;
    }
    for (int base_ = 0; base_ < NCMAX; base_ += 64) {
      int c = base_ + er;
      u16x8 v = (u16x8){0, 0, 0, 0, 0, 0, 0, 0};
      if (c < nloc) v = *(const u16x8*)(wcp + (size_t)c_pair[coff + c].x * PROJ + q * 8);
      *(u16x8*)(wc_s + c * WE_S_STRIDE + q * 8) = v;
    }
  }
  __syncthreads();

  // ---- T14: issue evT global loads into registers NOW; score hides latency ----
  float4 eva[8], evb[8];
#pragma unroll
  for (int it = 0; it < 8; it++) {
    int idx2 = it * 512 + t;
    int ep = idx2 & 127;
    int dq = idx2 >> 7;      // 0..31
    int d0 = dq * 4;
    int e0 = ep * 2;
    eva[it] = make_float4(0.f, 0.f, 0.f, 0.f);
    evb[it] = make_float4(0.f, 0.f, 0.f, 0.f);
    if (e0 < ne)     eva[it] = *(const float4*)(x + (size_t)ev_id[e0] * NHID + dsbase + d0);
    if (e0 + 1 < ne) evb[it] = *(const float4*)(x + (size_t)ev_id[e0 + 1] * NHID + dsbase + d0);
  }

  // ---- score phase: S = wc @ we^T via MFMA ----
  {
    f32x4 sa[16];
#pragma unroll
    for (int i = 0; i < 16; i++) sa[i] = (f32x4){0.f, 0.f, 0.f, 0.f};
    const unsigned short* arow = wc_s + ((w << 4) + ln) * WE_S_STRIDE;
#pragma unroll
    for (int ks = 0; ks < 2; ks++) {
      s16x8 af = *(const s16x8*)(arow + ks * 32 + kb * 8);
#pragma unroll
      for (int nt = 0; nt < 16; nt++) {
        if (nt < NT) {
          s16x8 bf = *(const s16x8*)(we_s + (nt * 16 + ln) * WE_S_STRIDE + ks * 32 + kb * 8);
          sa[nt] = __builtin_amdgcn_mfma_f32_16x16x32_bf16(af, bf, sa[nt], 0, 0, 0);
        }
      }
    }
#pragma unroll
    for (int r = 0; r < 4; r++) {
      int claim = (w << 4) + (kb << 2) + r;
      float mx = -1e30f;
#pragma unroll
      for (int nt = 0; nt < 16; nt++) {
        if (nt < NT) {
          float v = sa[nt][r];
          v = (nt * 16 + ln < ne) ? v : -1e30f;
          sa[nt][r] = v;
          mx = fmaxf(mx, v);
        }
      }
      mx = fmaxf(mx, __shfl_xor(mx, 1));
      mx = fmaxf(mx, __shfl_xor(mx, 2));
      mx = fmaxf(mx, __shfl_xor(mx, 4));
      mx = fmaxf(mx, __shfl_xor(mx, 8));
      float sum = 0.f;
#pragma unroll
      for (int nt = 0; nt < 16; nt++) {
        if (nt < NT) {
          float p = __expf(sa[nt][r] - mx);
          sa[nt][r] = p;
          sum += p;
        }
      }
      sum += __shfl_xor(sum, 1);
      sum += __shfl_xor(sum, 2);
      sum += __shfl_xor(sum, 4);
      sum += __shfl_xor(sum, 8);
      float inv = 1.f / sum;
#pragma unroll
      for (int nt = 0; nt < 16; nt++) {
        if (nt < NT)
          P_s[claim * P_S_STRIDE + nt * 16 + ln] = f2b(sa[nt][r] * inv);
      }
    }
  }
  __syncthreads();   // we_s dead; P_s ready; evT loads drained here

  // ---- write evT[d][e] bf16 from staged registers ----
#pragma unroll
  for (int it = 0; it < 8; it++) {
    int idx2 = it * 512 + t;
    int ep = idx2 & 127;
    int dq = idx2 >> 7;
    int d0 = dq * 4;
    float4 va = eva[it], vb = evb[it];
    evT32[(d0 + 0) * (P_S_STRIDE / 2) + ep] = (unsigned)f2b(va.x) | ((unsigned)f2b(vb.x) << 16);
    evT32[(d0 + 1) * (P_S_STRIDE / 2) + ep] = (unsigned)f2b(va.y) | ((unsigned)f2b(vb.y) << 16);
    evT32[(d0 + 2) * (P_S_STRIDE / 2) + ep] = (unsigned)f2b(va.z) | ((unsigned)f2b(vb.z) << 16);
    evT32[(d0 + 3) * (P_S_STRIDE / 2) + ep] = (unsigned)f2b(va.w) | ((unsigned)f2b(vb.w) << 16);
  }
  __syncthreads();

  // ---- T14: issue claim-row loads for pooled phase; PV hides latency ----
  int dq4 = (t & 31) * 4;
  int mg = t >> 5;     // 0..15
  float4 cl_r[8];
#pragma unroll
  for (int mi = 0; mi < 8; mi++) {
    int m = mg + mi * 16;
    cl_r[mi] = make_float4(0.f, 0.f, 0.f, 0.f);
    if (m < nloc)
      cl_r[mi] = *(const float4*)(x + (size_t)cl_id[m] * NHID + dsbase + dq4);
  }

  // ---- PV phase ----
  int mw = w >> 1, nw = w & 1;
  int m0 = mw * 32, n0 = nw * 64;
  f32x4 pc[8];
#pragma unroll
  for (int i = 0; i < 8; i++) pc[i] = (f32x4){0.f, 0.f, 0.f, 0.f};
  {
    const unsigned short* prow0 = P_s + (m0 + ln) * P_S_STRIDE + kb * 8;
    const unsigned short* prow1 = prow0 + 16 * P_S_STRIDE;
#pragma unroll
    for (int kt = 0; kt < 8; kt++) {
      if (kt < KT) {
        int k0 = kt * 32;
        s16x8 a0 = *(const s16x8*)(prow0 + k0);
        s16x8 a1 = *(const s16x8*)(prow1 + k0);
#pragma unroll
        for (int nt = 0; nt < 4; nt++) {
          s16x8 bf = *(const s16x8*)(evT + (n0 + nt * 16 + ln) * P_S_STRIDE + k0 + kb * 8);
          pc[nt]     = __builtin_amdgcn_mfma_f32_16x16x32_bf16(a0, bf, pc[nt], 0, 0, 0);
          pc[4 + nt] = __builtin_amdgcn_mfma_f32_16x16x32_bf16(a1, bf, pc[4 + nt], 0, 0, 0);
        }
      }
    }
  }
  __syncthreads();   // P_s dead from here; pp may reuse its region

  // ---- dump cn to LDS ----
#pragma unroll
  for (int mi = 0; mi < 2; mi++) {
#pragma unroll
    for (int nt = 0; nt < 4; nt++) {
      f32x4 v = pc[mi * 4 + nt];
#pragma unroll
      for (int r = 0; r < 4; r++)
        cn_s[(m0 + mi * 16 + (kb << 2) + r) * CN_S_STRIDE + n0 + nt * 16 + ln] = v[r];
    }
  }
  __syncthreads();

  // ---- pooled sums: staged claim regs + cn_s, partials into pp ----
  {
    float4 scl = make_float4(0.f, 0.f, 0.f, 0.f);
    float4 scn = make_float4(0.f, 0.f, 0.f, 0.f);
    float4 spr = make_float4(0.f, 0.f, 0.f, 0.f);
#pragma unroll
    for (int mi = 0; mi < 8; mi++) {
      int m = mg + mi * 16;
      if (m < nloc) {
        float4 cl = cl_r[mi];
        float4 cn = *(const float4*)(cn_s + m * CN_S_STRIDE + dq4);
        scl.x += cl.x; scl.y += cl.y; scl.z += cl.z; scl.w += cl.w;
        scn.x += cn.x; scn.y += cn.y; scn.z += cn.z; scn.w += cn.w;
        spr.x += cl.x * cn.x; spr.y += cl.y * cn.y;
        spr.z += cl.z * cn.z; spr.w += cl.w * cn.w;
      }
    }
    *(float4*)(pp + mg * 128 + dq4) = scl;
    *(float4*)(pp + 2048 + mg * 128 + dq4) = scn;
    *(float4*)(pp + 4096 + mg * 128 + dq4) = spr;
  }
  __syncthreads();

  // ---- fused mean-concat epilogue ----
  {
    int q = t >> 7, d = t & 127;
    float inv = 1.f / (float)max(ccnt_full, 1);
    float v = 0.f;
    if (q == 0) {
#pragma unroll
      for (int mg2 = 0; mg2 < 16; mg2++) v += pp[mg2 * 128 + d];
    } else if (q == 1) {
#pragma unroll
      for (int mg2 = 0; mg2 < 16; mg2++) v += pp[2048 + mg2 * 128 + d];
    } else if (q == 2) {
#pragma unroll
      for (int mg2 = 0; mg2 < 16; mg2++) v += pp[mg2 * 128 + d] - pp[2048 + mg2 * 128 + d];
    } else {
#pragma unroll
      for (int mg2 = 0; mg2 < 16; mg2++) v += pp[4096 + mg2 * 128 + d];
    }
    mcb[(size_t)g * 4 * NHID + q * NHID + dsbase + d] = f2b(v * inv);
  }
}

// ---------------- k_out: 32 blocks, 16-col n-tiles, 2-way K-split ----------------
__global__ __launch_bounds__(512) void k_out(
    const unsigned short* __restrict__ mc, const unsigned short* __restrict__ WaT,
    const float* __restrict__ ba, float* __restrict__ out) {
  __shared__ float red[2][64][16];   // 8KB
  int n0 = blockIdx.x * 16;
  int t = threadIdx.x, lane = t & 63, wv = t >> 6;
  int mh = wv & 3, kh = wv >> 2;
  int ln = lane & 15, kb = lane >> 4;
  f32x4 acc = (f32x4){0.f, 0.f, 0.f, 0.f};
  const unsigned short* arow = mc + (size_t)(mh * 16 + ln) * (4 * NHID) + kh * 1024;
  const unsigned short* wcol = WaT + (size_t)(n0 + ln) * (4 * NHID) + kh * 1024;
#pragma unroll 4
  for (int kt = 0; kt < 32; kt++) {
    int k0 = kt * 32 + kb * 8;
    s16x8 af = *(const s16x8*)(arow + k0);
    s16x8 bf = *(const s16x8*)(wcol + k0);
    acc = __builtin_amdgcn_mfma_f32_16x16x32_bf16(af, bf, acc, 0, 0, 0);
  }
#pragma unroll
  for (int r = 0; r < 4; r++)
    red[kh][mh * 16 + kb * 4 + r][ln] = acc[r];
  __syncthreads();
  for (int i = t; i < 1024; i += 512) {
    int row = i >> 4, col = i & 15;
    out[(size_t)row * NHID + n0 + col] = red[0][row][col] + red[1][row][col] + ba[n0 + col];
  }
}

extern "C" void kernel_launch(void* const* d_in, const int* in_sizes, int n_in,
                              void* d_out, int out_size, void* d_ws, size_t ws_size,
                              hipStream_t stream) {
  const float* x = (const float*)d_in[0];
  const int* batch = (const int*)d_in[1];
  const int* cidx = (const int*)d_in[2];
  const int* eidx = (const int*)d_in[3];
  const float* Wc = (const float*)d_in[4];
  const float* bc = (const float*)d_in[5];
  const float* We = (const float*)d_in[6];
  const float* be = (const float*)d_in[7];
  const float* Wa = (const float*)d_in[8];
  const float* ba = (const float*)d_in[9];
  float* out = (float*)d_out;

  char* w = (char*)d_ws;
  int* c_off = (int*)w;    w += NG * 4;
  int* c_cnt = (int*)w;    w += NG * 4;
  int* e_off = (int*)w;    w += NG * 4;
  int* e_cnt = (int*)w;    w += NG * 4;
  int2* c_pair = (int2*)w; w += (size_t)NC * 8;
  int2* e_pair = (int2*)w; w += (size_t)NEV * 8;
  unsigned short* wcp = (unsigned short*)w; w += (size_t)NC * PROJ * 2;
  unsigned short* wep = (unsigned short*)w; w += (size_t)NEV * PROJ * 2;
  unsigned short* WcT = (unsigned short*)w; w += (size_t)PROJ * NHID * 2;
  unsigned short* WeT = (unsigned short*)w; w += (size_t)PROJ * NHID * 2;
  unsigned short* WaT = (unsigned short*)w; w += (size_t)NHID * 4 * NHID * 2;
  unsigned short* mcb = (unsigned short*)w; w += (size_t)NG * 4 * NHID * 2;

  k_front<<<144, 256, 0, stream>>>(Wc, We, WcT, WeT, batch, cidx, eidx,
                                   c_off, c_cnt, c_pair, e_off, e_cnt, e_pair);
  k_proj<<<768 + 256, 256, 0, stream>>>(x, cidx, eidx, WcT, WeT, bc, be, Wa, WaT,
                                        wcp, wep);
  k_attn<<<NG * DSLICES, 512, 0, stream>>>(x, wcp, wep, c_off, c_cnt, c_pair,
                                           e_off, e_cnt, e_pair, mcb);
  k_out<<<32, 512, 0, stream>>>(mcb, WaT, ba, out);
}